// Round 4
// baseline (321.800 us; speedup 1.0000x reference)
//
#include <hip/hip_runtime.h>
#include <hip/hip_bf16.h>

#define HIDC 768
#define Hh   6
#define Dd   64
#define AHc  384
#define KSc  9
#define PADc 4
#define Bb   4
#define Ss   1024
#define MRr  (Bb * Ss)          // 4096

typedef __attribute__((ext_vector_type(8))) __bf16 bf16x8;
typedef __attribute__((ext_vector_type(4))) float  f32x4;

// async global->LDS, 16 bytes per lane; dest is wave-uniform base + lane*16
__device__ __forceinline__ void gl_lds16(const void* g, void* l) {
    __builtin_amdgcn_global_load_lds(
        (const __attribute__((address_space(1))) void*)g,
        (__attribute__((address_space(3))) void*)l, 16, 0, 0);
}

// split 8 consecutive f32 into hi/lo bf16 fragments
__device__ __forceinline__ void split8(const float* p, bf16x8& hi, bf16x8& lo) {
    float4 x0 = *(const float4*)p;
    float4 x1 = *(const float4*)(p + 4);
    float xs[8] = {x0.x, x0.y, x0.z, x0.w, x1.x, x1.y, x1.z, x1.w};
#pragma unroll
    for (int e = 0; e < 8; ++e) {
        __bf16 hv = (__bf16)xs[e];
        hi[e] = hv;
        lo[e] = (__bf16)(xs[e] - (float)hv);
    }
}

__device__ __forceinline__ void split8r(const float* xs, bf16x8& hi, bf16x8& lo) {
#pragma unroll
    for (int e = 0; e < 8; ++e) {
        __bf16 hv = (__bf16)xs[e];
        hi[e] = hv;
        lo[e] = (__bf16)(xs[e] - (float)hv);
    }
}

// convert 8 consecutive f32 to bf16 (hi only)
__device__ __forceinline__ bf16x8 cvt8(const float* p) {
    float4 x0 = *(const float4*)p;
    float4 x1 = *(const float4*)(p + 4);
    float xs[8] = {x0.x, x0.y, x0.z, x0.w, x1.x, x1.y, x1.z, x1.w};
    bf16x8 h;
#pragma unroll
    for (int e = 0; e < 8; ++e) h[e] = (__bf16)xs[e];
    return h;
}

// ---------------- depthwise conv over sequence (float4 over channels) ----------------
__global__ void k_depthwise(const float* __restrict__ Kin, const float* __restrict__ dww,
                            float* __restrict__ dwseq) {
    int idx = blockIdx.x * 256 + threadIdx.x;      // over B*S*HID/4
    if (idx >= Bb * Ss * HIDC / 4) return;
    int c4 = idx % (HIDC / 4);
    int s  = (idx / (HIDC / 4)) % Ss;
    int b  = idx / ((HIDC / 4) * Ss);
    int c  = c4 * 4;
    float wv[4][KSc];
#pragma unroll
    for (int j = 0; j < 4; ++j)
#pragma unroll
        for (int k = 0; k < KSc; ++k) wv[j][k] = dww[(c + j) * KSc + k];
    float4 acc = {0.f, 0.f, 0.f, 0.f};
#pragma unroll
    for (int k = 0; k < KSc; ++k) {
        int sp = s + k - PADc;
        if (sp >= 0 && sp < Ss) {
            float4 v = *(const float4*)&Kin[(size_t)(b * Ss + sp) * HIDC + c];
            acc.x += v.x * wv[0][k]; acc.y += v.y * wv[1][k];
            acc.z += v.z * wv[2][k]; acc.w += v.w * wv[3][k];
        }
    }
    *(float4*)&dwseq[(size_t)idx * 4] = acc;
}

// ---------------- transposed weight split (z=0..3): LDS-tiled ----------------
__global__ __launch_bounds__(256) void k_wsplit_t(const float* __restrict__ Wq, const float* __restrict__ Wk,
                                                  const float* __restrict__ Wv, const float* __restrict__ coW,
                                                  __bf16* __restrict__ Whi, __bf16* __restrict__ Wlo) {
    int z = blockIdx.z;
    const float* src = (z == 0) ? Wq : (z == 1) ? Wk : (z == 2) ? Wv : coW;
    int n0 = blockIdx.x * 64, k0 = blockIdx.y * 64;
    int tid = threadIdx.x;
    int r = tid >> 2, cq = tid & 3;
    __shared__ float tile[64][65];      // tile[k_local][n_local]
#pragma unroll
    for (int e = 0; e < 4; ++e) {
        float4 v = *(const float4*)&src[(size_t)(k0 + r) * AHc + n0 + cq * 16 + e * 4];
        tile[r][cq * 16 + e * 4 + 0] = v.x;
        tile[r][cq * 16 + e * 4 + 1] = v.y;
        tile[r][cq * 16 + e * 4 + 2] = v.z;
        tile[r][cq * 16 + e * 4 + 3] = v.w;
    }
    __syncthreads();
    float x[16];
#pragma unroll
    for (int e = 0; e < 16; ++e) x[e] = tile[cq * 16 + e][r];
    bf16x8 h0, l0, h1, l1;
    split8r(x, h0, l0);
    split8r(x + 8, h1, l1);
    size_t dst = ((size_t)(z * AHc + n0 + r)) * HIDC + k0 + cq * 16;
    *(bf16x8*)(Whi + dst)     = h0;
    *(bf16x8*)(Whi + dst + 8) = h1;
    *(bf16x8*)(Wlo + dst)     = l0;
    *(bf16x8*)(Wlo + dst + 8) = l1;
}

// ---------------- pw_w split (z=4, already [n][k]) ----------------
__global__ void k_wsplit_c(const float* __restrict__ pww,
                           __bf16* __restrict__ Whi, __bf16* __restrict__ Wlo) {
    int idx = blockIdx.x * 256 + threadIdx.x;      // over AHc*HIDC/8
    if (idx >= AHc * HIDC / 8) return;
    bf16x8 hi, lo;
    split8(pww + (size_t)idx * 8, hi, lo);
    size_t dst = (size_t)4 * AHc * HIDC + (size_t)idx * 8;
    *(bf16x8*)(Whi + dst) = hi;
    *(bf16x8*)(Wlo + dst) = lo;
}

// ---------------- ckW transpose: [384][54] -> [54][384] ----------------
__global__ void k_ckwT(const float* __restrict__ ckW, float* __restrict__ ckWt) {
    int idx = blockIdx.x * 256 + threadIdx.x;
    if (idx >= AHc * Hh * KSc) return;
    int o = idx / (Hh * KSc), t = idx % (Hh * KSc);
    ckWt[t * AHc + o] = ckW[idx];
}

// ---------------- Q/K split for k_attn: qh, kh+kl (overlaid on dead dwseq) -------
__global__ void k_qkvsplit(const float* __restrict__ mq, const float* __restrict__ mk,
                           __bf16* __restrict__ qh, __bf16* __restrict__ kh,
                           __bf16* __restrict__ kl) {
    const int n8 = MRr * AHc / 8;
    int idx = blockIdx.x * 256 + threadIdx.x;
    if (idx >= 2 * n8) return;
    int which = idx / n8, i8 = idx % n8;
    if (which == 0) {
        *(bf16x8*)(qh + (size_t)i8 * 8) = cvt8(mq + (size_t)i8 * 8);
    } else {
        bf16x8 hi, lo;
        split8(mk + (size_t)i8 * 8, hi, lo);
        *(bf16x8*)(kh + (size_t)i8 * 8) = hi;
        *(bf16x8*)(kl + (size_t)i8 * 8) = lo;
    }
}

// ---------------- V transpose: mv[b*S+s][h*D+d] -> vt[(b*H+h)*D+d][s] bf16 --------
__global__ __launch_bounds__(256) void k_vtrans(const float* __restrict__ mv,
                                                __bf16* __restrict__ vt) {
    int s0 = blockIdx.x * 64;
    int h = blockIdx.y % Hh, b = blockIdx.y / Hh;
    int tid = threadIdx.x;
    int r = tid >> 2, cq = tid & 3;
    __shared__ float tile[64][65];      // tile[s_local][d_local]
    const float* src = mv + (size_t)(b * Ss + s0 + r) * AHc + h * Dd + cq * 16;
#pragma unroll
    for (int e = 0; e < 4; ++e) {
        float4 v = *(const float4*)(src + e * 4);
        tile[r][cq * 16 + e * 4 + 0] = v.x;
        tile[r][cq * 16 + e * 4 + 1] = v.y;
        tile[r][cq * 16 + e * 4 + 2] = v.z;
        tile[r][cq * 16 + e * 4 + 3] = v.w;
    }
    __syncthreads();
    // r now = d_local (0..63), cq*16 = s_chunk
    bf16x8 o0, o1;
#pragma unroll
    for (int e = 0; e < 8; ++e) {
        o0[e] = (__bf16)tile[cq * 16 + e][r];
        o1[e] = (__bf16)tile[cq * 16 + 8 + e][r];
    }
    __bf16* dst = vt + ((size_t)((b * Hh + h) * Dd + r)) * Ss + s0 + cq * 16;
    *(bf16x8*)dst       = o0;
    *(bf16x8*)(dst + 8) = o1;
}

// ---------------- bias buffer: [5][384] ----------------
__global__ void k_bias(const float* __restrict__ cob, const float* __restrict__ sepb,
                       float* __restrict__ biasb) {
    int idx = blockIdx.x * 256 + threadIdx.x;
    if (idx >= 5 * AHc) return;
    int z = idx / AHc, n = idx % AHc;
    biasb[idx] = (z == 3) ? cob[n] : (z == 4) ? sepb[n] : 0.f;
}

// ---------------- batched MFMA GEMM (2-term: ah*bh + ah*bl) ----------------
// B staged via global_load_lds (linear LDS); A staged via cvt8 + ds_write (padded).
// XCD-chunked remap: 480 blocks, chunks of 60 per XCD -> A-tile-sharing blocks co-locate.
__global__ __launch_bounds__(256) void k_gemm5(
        const float* __restrict__ Q, const float* __restrict__ Kin,
        const float* __restrict__ V, const float* __restrict__ dwseq,
        const __bf16* __restrict__ Whi, const __bf16* __restrict__ Wlo,
        const float* __restrict__ biasb, float* __restrict__ Call) {
    __shared__ __attribute__((aligned(16))) __bf16 As_hi[128 * 40];   // padded
    __shared__ __attribute__((aligned(16))) __bf16 Bs_hi[128 * 32];   // linear (gl_lds)
    __shared__ __attribute__((aligned(16))) __bf16 Bs_lo[128 * 32];   // linear (gl_lds)

    int wg = blockIdx.x + 3 * (blockIdx.y + 32 * blockIdx.z);   // 0..479
    int n2 = (wg & 7) * 60 + (wg >> 3);                         // bijective (480%8==0)
    int bxx = n2 % 3, byy = (n2 / 3) % 32, z = n2 / 96;

    const float* Asrc = (z == 0) ? Q : (z == 1) ? Kin : (z <= 3) ? V : dwseq;
    int m0 = byy * 128, n0 = bxx * 128;
    int tid = threadIdx.x;
    int wave = tid >> 6, lane = tid & 63, quad = lane >> 4, l15 = lane & 15;

    // A staging coords (ds_write path)
    int sr = tid >> 1;
    int sk = (tid & 1) * 16;
    const float* Arow = Asrc + (size_t)(m0 + sr) * HIDC + sk;

    // B staging coords (global_load_lds path): instr p = wave*2+q covers rows p*16..p*16+15
    int brow = wave * 32 + (lane >> 2);          // q=0 row
    int bcol = (lane & 3) * 8;
    const __bf16* BhG0 = Whi + ((size_t)(z * AHc + n0 + brow)) * HIDC + bcol;
    const __bf16* BhG1 = BhG0 + (size_t)16 * HIDC;
    const __bf16* BlG0 = Wlo + ((size_t)(z * AHc + n0 + brow)) * HIDC + bcol;
    const __bf16* BlG1 = BlG0 + (size_t)16 * HIDC;
    __bf16* BhL0 = Bs_hi + (wave * 2 + 0) * 512;
    __bf16* BhL1 = Bs_hi + (wave * 2 + 1) * 512;
    __bf16* BlL0 = Bs_lo + (wave * 2 + 0) * 512;
    __bf16* BlL1 = Bs_lo + (wave * 2 + 1) * 512;

    f32x4 acc[4][4] = {};

    for (int k0 = 0; k0 < HIDC; k0 += 32) {
        const float* ap = Arow + k0;
        *(bf16x8*)&As_hi[sr * 40 + sk]     = cvt8(ap);
        *(bf16x8*)&As_hi[sr * 40 + sk + 8] = cvt8(ap + 8);
        gl_lds16(BhG0 + k0, BhL0);
        gl_lds16(BhG1 + k0, BhL1);
        gl_lds16(BlG0 + k0, BlL0);
        gl_lds16(BlG1 + k0, BlL1);
        __syncthreads();

        int mrow = (wave >> 1) * 64 + l15;
        int nrow = (wave & 1) * 64 + l15;
        bf16x8 ah[4], bh[4], bl[4];
#pragma unroll
        for (int mt = 0; mt < 4; ++mt)
            ah[mt] = *(bf16x8*)&As_hi[(mrow + mt * 16) * 40 + quad * 8];
#pragma unroll
        for (int nt = 0; nt < 4; ++nt) {
            bh[nt] = *(bf16x8*)&Bs_hi[(nrow + nt * 16) * 32 + quad * 8];
            bl[nt] = *(bf16x8*)&Bs_lo[(nrow + nt * 16) * 32 + quad * 8];
        }
#pragma unroll
        for (int mt = 0; mt < 4; ++mt)
#pragma unroll
            for (int nt = 0; nt < 4; ++nt) {
                acc[mt][nt] = __builtin_amdgcn_mfma_f32_16x16x32_bf16(ah[mt], bh[nt], acc[mt][nt], 0, 0, 0);
                acc[mt][nt] = __builtin_amdgcn_mfma_f32_16x16x32_bf16(ah[mt], bl[nt], acc[mt][nt], 0, 0, 0);
            }
        __syncthreads();
    }

    float* Cz = Call + (size_t)z * MRr * AHc;
    const float* bz = biasb + z * AHc;
#pragma unroll
    for (int nt = 0; nt < 4; ++nt) {
        int n = n0 + (wave & 1) * 64 + nt * 16 + l15;
        float bias = bz[n];
#pragma unroll
        for (int mt = 0; mt < 4; ++mt) {
#pragma unroll
            for (int r = 0; r < 4; ++r) {
                int m = m0 + (wave >> 1) * 64 + mt * 16 + quad * 4 + r;
                Cz[(size_t)m * AHc + n] = acc[mt][nt][r] + bias;
            }
        }
    }
}

// ---------------- conv_attn -> ck linear (float4, transposed W) -> softmax over KS ----
__global__ __launch_bounds__(64) void k_ck(const float* __restrict__ mkc, const float* __restrict__ mq,
                                           const float* __restrict__ ckWt, const float* __restrict__ ckb,
                                           float* __restrict__ ck_sm) {
    int row = blockIdx.x;            // b*S + s
    int tid = threadIdx.x;
    __shared__ __attribute__((aligned(16))) float ca[AHc];
    __shared__ float ckv[Hh * KSc];
    const float4* am = (const float4*)(mkc + (size_t)row * AHc);
    const float4* aq = (const float4*)(mq + (size_t)row * AHc);
#pragma unroll
    for (int o = 0; o < 2; ++o) {
        int i4 = tid + o * 64;
        if (i4 < AHc / 4) {
            float4 a = am[i4], b = aq[i4];
            float4 r;
            r.x = a.x * b.x; r.y = a.y * b.y; r.z = a.z * b.z; r.w = a.w * b.w;
            ((float4*)ca)[i4] = r;
        }
    }
    __syncthreads();
    if (tid < Hh * KSc) {
        float acc = ckb[tid];
        const float4* wr = (const float4*)(ckWt + tid * AHc);
        const float4* cr = (const float4*)ca;
#pragma unroll 4
        for (int o4 = 0; o4 < AHc / 4; ++o4) {
            float4 wv = wr[o4], cv = cr[o4];
            acc += wv.x * cv.x + wv.y * cv.y + wv.z * cv.z + wv.w * cv.w;
        }
        ckv[tid] = acc;
    }
    __syncthreads();
    if (tid < Hh) {
        float m = -3e38f;
#pragma unroll
        for (int k = 0; k < KSc; ++k) m = fmaxf(m, ckv[tid * KSc + k]);
        float e[KSc];
        float s = 0.f;
#pragma unroll
        for (int k = 0; k < KSc; ++k) { e[k] = expf(ckv[tid * KSc + k] - m); s += e[k]; }
        float inv = 1.f / s;
#pragma unroll
        for (int k = 0; k < KSc; ++k) ck_sm[(row * Hh + tid) * KSc + k] = e[k] * inv;
    }
}

// ---------------- dynamic conv output (float4) -> out[.., AH + h*D + d] ----------------
__global__ void k_convout(const float* __restrict__ co, const float* __restrict__ ck_sm,
                          float* __restrict__ out) {
    int idx = blockIdx.x * 256 + threadIdx.x;       // over B*S*AH/4
    if (idx >= Bb * Ss * AHc / 4) return;
    int d4 = idx & 15;
    int h  = (idx >> 4) % Hh;
    int s  = (idx / (AHc / 4)) % Ss;
    int b  = idx / ((AHc / 4) * Ss);
    int row = b * Ss + s;
    const float* ck = ck_sm + (size_t)(row * Hh + h) * KSc;
    float4 acc = {0.f, 0.f, 0.f, 0.f};
#pragma unroll
    for (int k = 0; k < KSc; ++k) {
        int sp = s + k - PADc;
        if (sp >= 0 && sp < Ss) {
            float4 v = *(const float4*)&co[(size_t)(b * Ss + sp) * AHc + h * Dd + d4 * 4];
            float wv = ck[k];
            acc.x += wv * v.x; acc.y += wv * v.y; acc.z += wv * v.z; acc.w += wv * v.w;
        }
    }
    *(float4*)&out[(size_t)row * (2 * AHc) + AHc + h * Dd + d4 * 4] = acc;
}

// ---------------- per-batch td softmax row ----------------
__global__ __launch_bounds__(256) void k_td(const float* __restrict__ td, const int* __restrict__ mask,
                                            float* __restrict__ td_sm) {
    int b = blockIdx.x;
    int tid = threadIdx.x;
    __shared__ float red[256];
    __shared__ float tv[Ss];
    float ls = 0.f;
    for (int j = tid; j < Ss; j += 256) {
        float v = td[b * Ss + j];
        tv[j] = v;
        ls += v * v;
    }
    red[tid] = ls; __syncthreads();
    for (int s = 128; s > 0; s >>= 1) { if (tid < s) red[tid] += red[tid + s]; __syncthreads(); }
    float norm = fmaxf(sqrtf(red[0]), 1e-12f);
    __syncthreads();
    float lm = -3e38f;
    for (int j = tid; j < Ss; j += 256) {
        float v = mask[b * Ss + j] ? tv[j] / norm : -1e4f;
        tv[j] = v;
        lm = fmaxf(lm, v);
    }
    red[tid] = lm; __syncthreads();
    for (int s = 128; s > 0; s >>= 1) { if (tid < s) red[tid] = fmaxf(red[tid], red[tid + s]); __syncthreads(); }
    float m = red[0]; __syncthreads();
    float lsum = 0.f;
    for (int j = tid; j < Ss; j += 256) {
        float e = expf(tv[j] - m);
        tv[j] = e;
        lsum += e;
    }
    red[tid] = lsum; __syncthreads();
    for (int s = 128; s > 0; s >>= 1) { if (tid < s) red[tid] += red[tid + s]; __syncthreads(); }
    float inv = 1.f / red[0];
    __syncthreads();
    for (int j = tid; j < Ss; j += 256)
        td_sm[b * Ss + j] = tv[j] * inv;
}

// ---------------- attention: 16 q-rows/block, 512 threads, XCD-chunked remap ------
// sc layout: row m (0..15) * 1024 floats, 16B-granule XOR swizzle for conflict-free
// b128 access in all three phases. Granule (4 floats) stays contiguous.
__device__ __forceinline__ int scix(int m, int j) {
    return m * 1024 + (j ^ (((m ^ (j >> 6)) & 7) << 2));
}

__global__ __launch_bounds__(512) void k_attn(const __bf16* __restrict__ qh,
                                              const __bf16* __restrict__ kh, const __bf16* __restrict__ kl,
                                              const __bf16* __restrict__ vt,
                                              const int* __restrict__ mask,
                                              const float* __restrict__ td_sm, const float* __restrict__ gammas,
                                              float* __restrict__ out) {
    __shared__ float sc[16 * 1024];      // 64 KB exactly
    // XCD-chunked block remap: all 64 blocks sharing one (b,h) K/V panel land on
    // one XCD (3 panels per XCD). grid = 64 x 24 = 1536 blocks, 1536 % 8 == 0.
    int wg = blockIdx.x + 64 * blockIdx.y;
    int n  = (wg & 7) * 192 + (wg >> 3);
    int bx = n & 63, by = n >> 6;
    int i0 = bx * 16;
    int h = by % Hh, b = by / Hh;
    int tid = threadIdx.x;
    int w = tid >> 6, lane = tid & 63, quad = lane >> 4, l15 = lane & 15;
    int jw = w * 128;                     // this wave's j-range [jw, jw+128)

    // ---- phase 1: QK^T via MFMA: q_hi*(k_hi + k_lo) ----
    bf16x8 a_hi[2];
    {
        size_t qoff = (size_t)(b * Ss + i0 + l15) * AHc + h * Dd + quad * 8;
        a_hi[0] = *(const bf16x8*)(qh + qoff);
        a_hi[1] = *(const bf16x8*)(qh + qoff + 32);
    }
#pragma unroll 2
    for (int t = 0; t < 8; ++t) {
        int jt = jw + t * 16;
        size_t koff = (size_t)(b * Ss + jt + l15) * AHc + h * Dd + quad * 8;
        f32x4 acc = {0.f, 0.f, 0.f, 0.f};
#pragma unroll
        for (int kc = 0; kc < 2; ++kc) {
            bf16x8 khv = *(const bf16x8*)(kh + koff + kc * 32);
            bf16x8 klv = *(const bf16x8*)(kl + koff + kc * 32);
            acc = __builtin_amdgcn_mfma_f32_16x16x32_bf16(a_hi[kc], khv, acc, 0, 0, 0);
            acc = __builtin_amdgcn_mfma_f32_16x16x32_bf16(a_hi[kc], klv, acc, 0, 0, 0);
        }
#pragma unroll
        for (int r = 0; r < 4; ++r)
            sc[scix(quad * 4 + r, jt + l15)] = acc[r] * 0.125f;   // C: col=l15, row=quad*4+r
    }
    __syncthreads();

    // ---- phase 2: softmax -> cumsum -> decay -> softmax2, wave owns rows w*2, w*2+1 ----
    const int* mrow = mask + b * Ss;
    const float* tdrow = td_sm + b * Ss;
    float gamma = -log1pf(expf(gammas[h]));   // -softplus
    int jb = lane << 4;
    __attribute__((aligned(16))) int marr[16];
    {
        const int4* mp = (const int4*)(mrow + jb);
#pragma unroll
        for (int k = 0; k < 4; ++k) ((int4*)marr)[k] = mp[k];
    }
    __attribute__((aligned(16))) float tdv[16];
    {
        const float4* tp = (const float4*)(tdrow + jb);
#pragma unroll
        for (int k = 0; k < 4; ++k) ((float4*)tdv)[k] = tp[k];
    }

#pragma unroll
    for (int r4 = 0; r4 < 2; ++r4) {
        int m = w * 2 + r4;
        int i = i0 + m;
        __attribute__((aligned(16))) float s[16];
        float p[16];
#pragma unroll
        for (int g = 0; g < 4; ++g)
            *(f32x4*)(s + 4 * g) = *(const f32x4*)&sc[scix(m, jb + 4 * g)];
        float mx = -1e30f;
#pragma unroll
        for (int jj = 0; jj < 16; ++jj) mx = fmaxf(mx, marr[jj] ? s[jj] : -1e30f);
        mx = fmaxf(mx, __shfl_xor(mx, 1));  mx = fmaxf(mx, __shfl_xor(mx, 2));
        mx = fmaxf(mx, __shfl_xor(mx, 4));  mx = fmaxf(mx, __shfl_xor(mx, 8));
        mx = fmaxf(mx, __shfl_xor(mx, 16)); mx = fmaxf(mx, __shfl_xor(mx, 32));
#pragma unroll
        for (int jj = 0; jj < 16; ++jj) p[jj] = marr[jj] ? __expf(s[jj] - mx) : 0.f;
#pragma unroll
        for (int jj = 1; jj < 16; ++jj) p[jj] += p[jj - 1];
        float t = p[15];
        float incl = t;
#pragma unroll
        for (int dlt = 1; dlt < 64; dlt <<= 1) {
            float v = __shfl_up(incl, dlt);
            if (lane >= dlt) incl += v;
        }
        float off = incl - t;
        float tot = __shfl(incl, 63);
        float inv = 1.f / fmaxf(tot, 1e-30f);
        float mx2 = -1e30f;
#pragma unroll
        for (int jj = 0; jj < 16; ++jj) {
            int j = jb + jj;
            float cum = p[jj] + off;
            float pos = fabsf((float)(j - i));
            float ds = sqrtf(fmaxf((tot - cum) * inv * pos, 0.f));
            float te = fminf(fmaxf(__expf(ds * gamma), 1e-5f), 1e5f);
            float mult = te - ((j < i) ? tdv[jj] : 0.f);
            float s2 = marr[jj] ? s[jj] * mult : -1e8f;
            s[jj] = s2;
            mx2 = fmaxf(mx2, s2);
        }
        mx2 = fmaxf(mx2, __shfl_xor(mx2, 1));  mx2 = fmaxf(mx2, __shfl_xor(mx2, 2));
        mx2 = fmaxf(mx2, __shfl_xor(mx2, 4));  mx2 = fmaxf(mx2, __shfl_xor(mx2, 8));
        mx2 = fmaxf(mx2, __shfl_xor(mx2, 16)); mx2 = fmaxf(mx2, __shfl_xor(mx2, 32));
        float sm = 0.f;
#pragma unroll
        for (int jj = 0; jj < 16; ++jj) { s[jj] = __expf(s[jj] - mx2); sm += s[jj]; }
        sm += __shfl_xor(sm, 1);  sm += __shfl_xor(sm, 2);
        sm += __shfl_xor(sm, 4);  sm += __shfl_xor(sm, 8);
        sm += __shfl_xor(sm, 16); sm += __shfl_xor(sm, 32);
        float inv2 = 1.f / sm;
#pragma unroll
        for (int jj = 0; jj < 16; ++jj) s[jj] *= inv2;
#pragma unroll
        for (int g = 0; g < 4; ++g)
            *(f32x4*)&sc[scix(m, jb + 4 * g)] = *(const f32x4*)(s + 4 * g);
    }
    __syncthreads();

    // ---- phase 3: PV via MFMA: (p_hi + p_lo) * v_hi; V pre-transposed bf16 [d][j] ----
    f32x4 oacc[4] = {};
    const __bf16* vtb = vt + (size_t)(b * Hh + h) * Dd * Ss;
#pragma unroll
    for (int kc = 0; kc < 4; ++kc) {
        int j0 = jw + kc * 32 + quad * 8;        // this lane's 8 j indices (k = quad*8+e)
        __attribute__((aligned(16))) float x[8];
        *(f32x4*)x       = *(const f32x4*)&sc[scix(l15, j0)];
        *(f32x4*)(x + 4) = *(const f32x4*)&sc[scix(l15, j0 + 4)];
        bf16x8 p_hi, p_lo;
        split8r(x, p_hi, p_lo);
#pragma unroll
        for (int nt = 0; nt < 4; ++nt) {
            int d = nt * 16 + l15;
            bf16x8 vv = *(const bf16x8*)(vtb + (size_t)d * Ss + j0);
            oacc[nt] = __builtin_amdgcn_mfma_f32_16x16x32_bf16(p_hi, vv, oacc[nt], 0, 0, 0);
            oacc[nt] = __builtin_amdgcn_mfma_f32_16x16x32_bf16(p_lo, vv, oacc[nt], 0, 0, 0);
        }
    }
    __syncthreads();                      // all waves done reading sc before reuse
#pragma unroll
    for (int nt = 0; nt < 4; ++nt)
#pragma unroll
        for (int r = 0; r < 4; ++r)
            sc[w * 1024 + (quad * 4 + r) * 64 + nt * 16 + l15] = oacc[nt][r];
    __syncthreads();
#pragma unroll
    for (int e = 0; e < 2; ++e) {
        int idx = e * 512 + tid;
        int m = idx >> 6, dd = idx & 63;
        float v = 0.f;
#pragma unroll
        for (int ww = 0; ww < 8; ++ww) v += sc[ww * 1024 + idx];
        out[(size_t)(b * Ss + i0 + m) * (2 * AHc) + h * Dd + dd] = v;
    }
}

extern "C" void kernel_launch(void* const* d_in, const int* in_sizes, int n_in,
                              void* d_out, int out_size, void* d_ws, size_t ws_size,
                              hipStream_t stream) {
    const float* Q    = (const float*)d_in[0];
    const float* Kin  = (const float*)d_in[1];
    const float* V    = (const float*)d_in[2];
    const float* td   = (const float*)d_in[3];
    const int*   mask = (const int*)d_in[4];
    const float* Wq   = (const float*)d_in[5];
    const float* Wk   = (const float*)d_in[6];
    const float* Wv   = (const float*)d_in[7];
    const float* dww  = (const float*)d_in[8];
    const float* pww  = (const float*)d_in[9];
    const float* sepb = (const float*)d_in[10];
    const float* ckW  = (const float*)d_in[11];
    const float* ckb  = (const float*)d_in[12];
    const float* coW  = (const float*)d_in[13];
    const float* cob  = (const float*)d_in[14];
    const float* gam  = (const float*)d_in[15];
    float* out = (float*)d_out;
    float* ws = (float*)d_ws;

    float* mq    = ws;                              // z=0 C
    float* mk    = mq    + (size_t)MRr * AHc;       // z=1
    float* mv    = mk    + (size_t)MRr * AHc;       // z=2
    float* co    = mv    + (size_t)MRr * AHc;       // z=3
    float* mkc   = co    + (size_t)MRr * AHc;       // z=4
    float* dwseq = mkc   + (size_t)MRr * AHc;       // MR*HID f32 (dead after k_gemm5)
    float* cksm  = dwseq + (size_t)MRr * HIDC;      // MR*H*KS
    float* tdsm  = cksm  + (size_t)MRr * Hh * KSc;  // B*S
    float* biasb = tdsm  + (size_t)Bb * Ss;         // 5*384
    float* ckwt  = biasb + (size_t)5 * AHc;         // 54*384 transposed ck weights

    // d_out doubles as scratch for split weights (consumed by k_gemm5, then overwritten)
    __bf16* Whi = (__bf16*)d_out;
    __bf16* Wlo = Whi + (size_t)5 * AHc * HIDC;
    // qh/kh/kl/vt overlay the dead dwseq region: 4 * MR*AH bf16 == MR*HID f32 exactly
    __bf16* qh = (__bf16*)dwseq;
    __bf16* kh = qh + (size_t)MRr * AHc;
    __bf16* kl = kh + (size_t)MRr * AHc;
    __bf16* vt = kl + (size_t)MRr * AHc;            // transposed V [(b*H+h)*D+d][s]

    dim3 gt(AHc / 64, HIDC / 64, 4);    // 6 x 12 x 4
    k_wsplit_t<<<gt, 256, 0, stream>>>(Wq, Wk, Wv, coW, Whi, Wlo);
    k_wsplit_c<<<(AHc * HIDC / 8 + 255) / 256, 256, 0, stream>>>(pww, Whi, Wlo);
    k_ckwT<<<(AHc * Hh * KSc + 255) / 256, 256, 0, stream>>>(ckW, ckwt);
    k_depthwise<<<(MRr * HIDC / 4 + 255) / 256, 256, 0, stream>>>(Kin, dww, dwseq);
    k_bias<<<(5 * AHc + 255) / 256, 256, 0, stream>>>(cob, sepb, biasb);

    dim3 gg(AHc / 128, MRr / 128, 5);   // 3 x 32 x 5
    k_gemm5<<<gg, 256, 0, stream>>>(Q, Kin, V, dwseq, Whi, Wlo, biasb, mq);

    k_qkvsplit<<<(2 * MRr * AHc / 8 + 255) / 256, 256, 0, stream>>>(mq, mk, qh, kh, kl);
    k_vtrans<<<dim3(Ss / 64, Bb * Hh), 256, 0, stream>>>(mv, vt);
    k_ck<<<MRr, 64, 0, stream>>>(mkc, mq, ckwt, ckb, cksm);
    k_convout<<<(MRr * AHc / 4 + 255) / 256, 256, 0, stream>>>(co, cksm, out);
    k_td<<<Bb, 256, 0, stream>>>(td, mask, tdsm);

    dim3 ga(Ss / 16, Bb * Hh);          // 64 x 24
    k_attn<<<ga, 512, 0, stream>>>(qh, kh, kl, vt, mask, tdsm, gam, out);
}

// Round 6
// 303.407 us; speedup vs baseline: 1.0606x; 1.0606x over previous
//
#include <hip/hip_runtime.h>
#include <hip/hip_bf16.h>

#define HIDC 768
#define Hh   6
#define Dd   64
#define AHc  384
#define KSc  9
#define PADc 4
#define Bb   4
#define Ss   1024
#define MRr  (Bb * Ss)          // 4096

typedef __attribute__((ext_vector_type(8))) __bf16 bf16x8;
typedef __attribute__((ext_vector_type(4))) __bf16 bf16x4;
typedef __attribute__((ext_vector_type(4))) float  f32x4;

// async global->LDS, 16 bytes per lane; dest = wave-uniform base + lane*16
__device__ __forceinline__ void gl_lds16(const void* g, void* l) {
    __builtin_amdgcn_global_load_lds(
        (const __attribute__((address_space(1))) void*)g,
        (__attribute__((address_space(3))) void*)l, 16, 0, 0);
}

// split 8 consecutive f32 into hi/lo bf16 fragments
__device__ __forceinline__ void split8(const float* p, bf16x8& hi, bf16x8& lo) {
    float4 x0 = *(const float4*)p;
    float4 x1 = *(const float4*)(p + 4);
    float xs[8] = {x0.x, x0.y, x0.z, x0.w, x1.x, x1.y, x1.z, x1.w};
#pragma unroll
    for (int e = 0; e < 8; ++e) {
        __bf16 hv = (__bf16)xs[e];
        hi[e] = hv;
        lo[e] = (__bf16)(xs[e] - (float)hv);
    }
}

__device__ __forceinline__ void split8r(const float* xs, bf16x8& hi, bf16x8& lo) {
#pragma unroll
    for (int e = 0; e < 8; ++e) {
        __bf16 hv = (__bf16)xs[e];
        hi[e] = hv;
        lo[e] = (__bf16)(xs[e] - (float)hv);
    }
}

// convert 8 consecutive f32 to bf16 (hi only)
__device__ __forceinline__ bf16x8 cvt8(const float* p) {
    float4 x0 = *(const float4*)p;
    float4 x1 = *(const float4*)(p + 4);
    float xs[8] = {x0.x, x0.y, x0.z, x0.w, x1.x, x1.y, x1.z, x1.w};
    bf16x8 h;
#pragma unroll
    for (int e = 0; e < 8; ++e) h[e] = (__bf16)xs[e];
    return h;
}

// ---------------- depthwise conv over sequence -> bf16 output ----------------
__global__ void k_depthwise(const float* __restrict__ Kin, const float* __restrict__ dww,
                            __bf16* __restrict__ dwbf) {
    int idx = blockIdx.x * 256 + threadIdx.x;      // over B*S*HID/4
    if (idx >= Bb * Ss * HIDC / 4) return;
    int c4 = idx % (HIDC / 4);
    int s  = (idx / (HIDC / 4)) % Ss;
    int b  = idx / ((HIDC / 4) * Ss);
    int c  = c4 * 4;
    float wv[4][KSc];
#pragma unroll
    for (int j = 0; j < 4; ++j)
#pragma unroll
        for (int k = 0; k < KSc; ++k) wv[j][k] = dww[(c + j) * KSc + k];
    float4 acc = {0.f, 0.f, 0.f, 0.f};
#pragma unroll
    for (int k = 0; k < KSc; ++k) {
        int sp = s + k - PADc;
        if (sp >= 0 && sp < Ss) {
            float4 v = *(const float4*)&Kin[(size_t)(b * Ss + sp) * HIDC + c];
            acc.x += v.x * wv[0][k]; acc.y += v.y * wv[1][k];
            acc.z += v.z * wv[2][k]; acc.w += v.w * wv[3][k];
        }
    }
    bf16x4 o = {(__bf16)acc.x, (__bf16)acc.y, (__bf16)acc.z, (__bf16)acc.w};
    *(bf16x4*)(dwbf + (size_t)idx * 4) = o;
}

// ---------------- transposed weight split (z=0..3): LDS-tiled ----------------
__global__ __launch_bounds__(256) void k_wsplit_t(const float* __restrict__ Wq, const float* __restrict__ Wk,
                                                  const float* __restrict__ Wv, const float* __restrict__ coW,
                                                  __bf16* __restrict__ Whi, __bf16* __restrict__ Wlo) {
    int z = blockIdx.z;
    const float* src = (z == 0) ? Wq : (z == 1) ? Wk : (z == 2) ? Wv : coW;
    int n0 = blockIdx.x * 64, k0 = blockIdx.y * 64;
    int tid = threadIdx.x;
    int r = tid >> 2, cq = tid & 3;
    __shared__ float tile[64][65];      // tile[k_local][n_local]
#pragma unroll
    for (int e = 0; e < 4; ++e) {
        float4 v = *(const float4*)&src[(size_t)(k0 + r) * AHc + n0 + cq * 16 + e * 4];
        tile[r][cq * 16 + e * 4 + 0] = v.x;
        tile[r][cq * 16 + e * 4 + 1] = v.y;
        tile[r][cq * 16 + e * 4 + 2] = v.z;
        tile[r][cq * 16 + e * 4 + 3] = v.w;
    }
    __syncthreads();
    float x[16];
#pragma unroll
    for (int e = 0; e < 16; ++e) x[e] = tile[cq * 16 + e][r];
    bf16x8 h0, l0, h1, l1;
    split8r(x, h0, l0);
    split8r(x + 8, h1, l1);
    size_t dst = ((size_t)(z * AHc + n0 + r)) * HIDC + k0 + cq * 16;
    *(bf16x8*)(Whi + dst)     = h0;
    *(bf16x8*)(Whi + dst + 8) = h1;
    *(bf16x8*)(Wlo + dst)     = l0;
    *(bf16x8*)(Wlo + dst + 8) = l1;
}

// ---------------- pw_w split (z=4, already [n][k]) ----------------
__global__ void k_wsplit_c(const float* __restrict__ pww,
                           __bf16* __restrict__ Whi, __bf16* __restrict__ Wlo) {
    int idx = blockIdx.x * 256 + threadIdx.x;      // over AHc*HIDC/8
    if (idx >= AHc * HIDC / 8) return;
    bf16x8 hi, lo;
    split8(pww + (size_t)idx * 8, hi, lo);
    size_t dst = (size_t)4 * AHc * HIDC + (size_t)idx * 8;
    *(bf16x8*)(Whi + dst) = hi;
    *(bf16x8*)(Wlo + dst) = lo;
}

// ---------------- A-operand pre-convert: Q -> qbf, V -> vbf (bf16 hi) ----------------
__global__ void k_absplit(const float* __restrict__ Q, const float* __restrict__ V,
                          __bf16* __restrict__ qbf, __bf16* __restrict__ vbf) {
    const int n8 = MRr * HIDC / 8;
    int idx = blockIdx.x * 256 + threadIdx.x;
    if (idx >= 2 * n8) return;
    if (idx < n8) {
        *(bf16x8*)(qbf + (size_t)idx * 8) = cvt8(Q + (size_t)idx * 8);
    } else {
        int i = idx - n8;
        *(bf16x8*)(vbf + (size_t)i * 8) = cvt8(V + (size_t)i * 8);
    }
}

// ---------------- qh conversion (mq f32 -> bf16) ----------------
__global__ void k_qkvsplit(const float* __restrict__ mq, __bf16* __restrict__ qh) {
    int idx = blockIdx.x * 256 + threadIdx.x;
    if (idx >= MRr * AHc / 8) return;
    *(bf16x8*)(qh + (size_t)idx * 8) = cvt8(mq + (size_t)idx * 8);
}

// ---------------- V transpose: mv[b*S+s][h*D+d] -> vt[(b*H+h)*D+d][s] bf16 --------
__global__ __launch_bounds__(256) void k_vtrans(const float* __restrict__ mv,
                                                __bf16* __restrict__ vt) {
    int s0 = blockIdx.x * 64;
    int h = blockIdx.y % Hh, b = blockIdx.y / Hh;
    int tid = threadIdx.x;
    int r = tid >> 2, cq = tid & 3;
    __shared__ float tile[64][65];      // tile[s_local][d_local]
    const float* src = mv + (size_t)(b * Ss + s0 + r) * AHc + h * Dd + cq * 16;
#pragma unroll
    for (int e = 0; e < 4; ++e) {
        float4 v = *(const float4*)(src + e * 4);
        tile[r][cq * 16 + e * 4 + 0] = v.x;
        tile[r][cq * 16 + e * 4 + 1] = v.y;
        tile[r][cq * 16 + e * 4 + 2] = v.z;
        tile[r][cq * 16 + e * 4 + 3] = v.w;
    }
    __syncthreads();
    // r now = d_local (0..63), cq*16 = s_chunk
    bf16x8 o0, o1;
#pragma unroll
    for (int e = 0; e < 8; ++e) {
        o0[e] = (__bf16)tile[cq * 16 + e][r];
        o1[e] = (__bf16)tile[cq * 16 + 8 + e][r];
    }
    __bf16* dst = vt + ((size_t)((b * Hh + h) * Dd + r)) * Ss + s0 + cq * 16;
    *(bf16x8*)dst       = o0;
    *(bf16x8*)(dst + 8) = o1;
}

// ---------------- bias buffer: [5][384] ----------------
__global__ void k_bias(const float* __restrict__ cob, const float* __restrict__ sepb,
                       float* __restrict__ biasb) {
    int idx = blockIdx.x * 256 + threadIdx.x;
    if (idx >= 5 * AHc) return;
    int z = idx / AHc, n = idx % AHc;
    biasb[idx] = (z == 3) ? cob[n] : (z == 4) ? sepb[n] : 0.f;
}

// ---------------- batched MFMA GEMM (2-term: ah*(bh+bl)) ----------------
// A (bf16 pre-split, except z=1) and B both staged via global_load_lds into linear
// [128][32] LDS with granule XOR swizzle: slot s of row r holds global granule
// s ^ (r & 3)  [4 granules/row -> mask MUST be &3; &7 reads the wrong k-chunk].
// Read granule q of row r at slot q ^ (r&3). Conflict-uniform (8 lanes/bank-quad).
__global__ __launch_bounds__(256) void k_gemm5(
        const __bf16* __restrict__ qbf, const float* __restrict__ Kin,
        const __bf16* __restrict__ vbf, const __bf16* __restrict__ dwbf,
        const __bf16* __restrict__ Whi, const __bf16* __restrict__ Wlo,
        const float* __restrict__ biasb, float* __restrict__ Call,
        __bf16* __restrict__ kh, __bf16* __restrict__ kl) {
    __shared__ __attribute__((aligned(16))) __bf16 As [128 * 32];
    __shared__ __attribute__((aligned(16))) __bf16 BsH[128 * 32];
    __shared__ __attribute__((aligned(16))) __bf16 BsL[128 * 32];

    int wg = blockIdx.x + 3 * (blockIdx.y + 32 * blockIdx.z);   // 0..479
    int n2 = (wg & 7) * 60 + (wg >> 3);                         // bijective (480%8==0)
    int bxx = n2 % 3, byy = (n2 / 3) % 32, z = n2 / 96;

    int m0 = byy * 128, n0 = bxx * 128;
    int tid = threadIdx.x;
    int wave = tid >> 6, lane = tid & 63, quad = lane >> 4, l15 = lane & 15;

    int lrow = lane >> 2;                                // 0..15 within instr
    int lswz = 8 * ((lane & 3) ^ (lrow & 3));            // swizzled src granule offset

    // B staging (gl_lds): instr p = wave*2+q covers rows p*16..p*16+15
    int brow = wave * 32 + lrow;
    const __bf16* BhG0 = Whi + ((size_t)(z * AHc + n0 + brow)) * HIDC + lswz;
    const __bf16* BhG1 = BhG0 + (size_t)16 * HIDC;
    const __bf16* BlG0 = Wlo + ((size_t)(z * AHc + n0 + brow)) * HIDC + lswz;
    const __bf16* BlG1 = BlG0 + (size_t)16 * HIDC;
    __bf16* BhL0 = BsH + (wave * 2 + 0) * 512;
    __bf16* BhL1 = BsH + (wave * 2 + 1) * 512;
    __bf16* BlL0 = BsL + (wave * 2 + 0) * 512;
    __bf16* BlL1 = BsL + (wave * 2 + 1) * 512;

    // A staging (gl_lds path, z != 1)
    const __bf16* Abf = (z == 0) ? qbf : (z == 4) ? dwbf : vbf;
    const __bf16* AG0 = Abf + ((size_t)(m0 + wave * 32 + lrow)) * HIDC + lswz;
    const __bf16* AG1 = AG0 + (size_t)16 * HIDC;
    __bf16* AL0 = As + (wave * 2 + 0) * 512;
    __bf16* AL1 = As + (wave * 2 + 1) * 512;

    // A staging (f32 path, z == 1): swizzled ds_write of cvt'd granule pairs
    int sr = tid >> 1;
    int sk = (tid & 1) * 16;
    const float* Arow = Kin + (size_t)(m0 + sr) * HIDC + sk;
    int g0 = sk >> 3;                                    // 0 or 2
    int d0 = sr * 32 + ((g0       ^ (sr & 3)) * 8);
    int d1 = sr * 32 + (((g0 + 1) ^ (sr & 3)) * 8);

    int swz = (quad ^ (l15 & 3)) * 8;                    // swizzled read offset
    f32x4 acc[4][4] = {};

    for (int k0 = 0; k0 < HIDC; k0 += 32) {
        if (z == 1) {
            const float* ap = Arow + k0;
            *(bf16x8*)&As[d0] = cvt8(ap);
            *(bf16x8*)&As[d1] = cvt8(ap + 8);
        } else {
            gl_lds16(AG0 + k0, AL0);
            gl_lds16(AG1 + k0, AL1);
        }
        gl_lds16(BhG0 + k0, BhL0);
        gl_lds16(BhG1 + k0, BhL1);
        gl_lds16(BlG0 + k0, BlL0);
        gl_lds16(BlG1 + k0, BlL1);
        __syncthreads();

        int mrow = (wave >> 1) * 64 + l15;
        int nrow = (wave & 1) * 64 + l15;
        bf16x8 ah[4], bh[4], bl[4];
#pragma unroll
        for (int mt = 0; mt < 4; ++mt)
            ah[mt] = *(bf16x8*)&As[(mrow + mt * 16) * 32 + swz];
#pragma unroll
        for (int nt = 0; nt < 4; ++nt) {
            bh[nt] = *(bf16x8*)&BsH[(nrow + nt * 16) * 32 + swz];
            bl[nt] = *(bf16x8*)&BsL[(nrow + nt * 16) * 32 + swz];
        }
#pragma unroll
        for (int mt = 0; mt < 4; ++mt)
#pragma unroll
            for (int nt = 0; nt < 4; ++nt) {
                acc[mt][nt] = __builtin_amdgcn_mfma_f32_16x16x32_bf16(ah[mt], bh[nt], acc[mt][nt], 0, 0, 0);
                acc[mt][nt] = __builtin_amdgcn_mfma_f32_16x16x32_bf16(ah[mt], bl[nt], acc[mt][nt], 0, 0, 0);
            }
        __syncthreads();
    }

    if (z == 1) {
        // bias for z=1 is zero; emit kh/kl bf16 directly
#pragma unroll
        for (int nt = 0; nt < 4; ++nt) {
            int n = n0 + (wave & 1) * 64 + nt * 16 + l15;
#pragma unroll
            for (int mt = 0; mt < 4; ++mt) {
#pragma unroll
                for (int r = 0; r < 4; ++r) {
                    int m = m0 + (wave >> 1) * 64 + mt * 16 + quad * 4 + r;
                    float v = acc[mt][nt][r];
                    __bf16 hv = (__bf16)v;
                    kh[(size_t)m * AHc + n] = hv;
                    kl[(size_t)m * AHc + n] = (__bf16)(v - (float)hv);
                }
            }
        }
    } else {
        float* Cz = Call + (size_t)z * MRr * AHc;
        const float* bz = biasb + z * AHc;
#pragma unroll
        for (int nt = 0; nt < 4; ++nt) {
            int n = n0 + (wave & 1) * 64 + nt * 16 + l15;
            float bias = bz[n];
#pragma unroll
            for (int mt = 0; mt < 4; ++mt) {
#pragma unroll
                for (int r = 0; r < 4; ++r) {
                    int m = m0 + (wave >> 1) * 64 + mt * 16 + quad * 4 + r;
                    Cz[(size_t)m * AHc + n] = acc[mt][nt][r] + bias;
                }
            }
        }
    }
}

// ---------------- conv_attn -> ck linear -> per-head softmax over KS ----------------
__global__ __launch_bounds__(64) void k_ck(const float* __restrict__ mkc, const float* __restrict__ mq,
                                           const float* __restrict__ ckW, const float* __restrict__ ckb,
                                           float* __restrict__ ck_sm) {
    int row = blockIdx.x;            // b*S + s
    int tid = threadIdx.x;
    __shared__ float ca[AHc];
    __shared__ float ckv[Hh * KSc];
    for (int o = tid; o < AHc; o += 64)
        ca[o] = mkc[row * AHc + o] * mq[row * AHc + o];
    __syncthreads();
    if (tid < Hh * KSc) {
        float acc = ckb[tid];
        for (int o = 0; o < AHc; ++o)
            acc += ca[o] * ckW[o * (Hh * KSc) + tid];
        ckv[tid] = acc;
    }
    __syncthreads();
    if (tid < Hh) {
        float m = -3e38f;
#pragma unroll
        for (int k = 0; k < KSc; ++k) m = fmaxf(m, ckv[tid * KSc + k]);
        float e[KSc];
        float s = 0.f;
#pragma unroll
        for (int k = 0; k < KSc; ++k) { e[k] = expf(ckv[tid * KSc + k] - m); s += e[k]; }
        float inv = 1.f / s;
#pragma unroll
        for (int k = 0; k < KSc; ++k) ck_sm[(row * Hh + tid) * KSc + k] = e[k] * inv;
    }
}

// ---------------- dynamic conv output (float4) -> out[.., AH + h*D + d] ----------------
__global__ void k_convout(const float* __restrict__ co, const float* __restrict__ ck_sm,
                          float* __restrict__ out) {
    int idx = blockIdx.x * 256 + threadIdx.x;       // over B*S*AH/4
    if (idx >= Bb * Ss * AHc / 4) return;
    int d4 = idx & 15;
    int h  = (idx >> 4) % Hh;
    int s  = (idx / (AHc / 4)) % Ss;
    int b  = idx / ((AHc / 4) * Ss);
    int row = b * Ss + s;
    const float* ck = ck_sm + (size_t)(row * Hh + h) * KSc;
    float4 acc = {0.f, 0.f, 0.f, 0.f};
#pragma unroll
    for (int k = 0; k < KSc; ++k) {
        int sp = s + k - PADc;
        if (sp >= 0 && sp < Ss) {
            float4 v = *(const float4*)&co[(size_t)(b * Ss + sp) * AHc + h * Dd + d4 * 4];
            float wv = ck[k];
            acc.x += wv * v.x; acc.y += wv * v.y; acc.z += wv * v.z; acc.w += wv * v.w;
        }
    }
    *(float4*)&out[(size_t)row * (2 * AHc) + AHc + h * Dd + d4 * 4] = acc;
}

// ---------------- per-batch td softmax row ----------------
__global__ __launch_bounds__(256) void k_td(const float* __restrict__ td, const int* __restrict__ mask,
                                            float* __restrict__ td_sm) {
    int b = blockIdx.x;
    int tid = threadIdx.x;
    __shared__ float red[256];
    __shared__ float tv[Ss];
    float ls = 0.f;
    for (int j = tid; j < Ss; j += 256) {
        float v = td[b * Ss + j];
        tv[j] = v;
        ls += v * v;
    }
    red[tid] = ls; __syncthreads();
    for (int s = 128; s > 0; s >>= 1) { if (tid < s) red[tid] += red[tid + s]; __syncthreads(); }
    float norm = fmaxf(sqrtf(red[0]), 1e-12f);
    __syncthreads();
    float lm = -3e38f;
    for (int j = tid; j < Ss; j += 256) {
        float v = mask[b * Ss + j] ? tv[j] / norm : -1e4f;
        tv[j] = v;
        lm = fmaxf(lm, v);
    }
    red[tid] = lm; __syncthreads();
    for (int s = 128; s > 0; s >>= 1) { if (tid < s) red[tid] = fmaxf(red[tid], red[tid + s]); __syncthreads(); }
    float m = red[0]; __syncthreads();
    float lsum = 0.f;
    for (int j = tid; j < Ss; j += 256) {
        float e = expf(tv[j] - m);
        tv[j] = e;
        lsum += e;
    }
    red[tid] = lsum; __syncthreads();
    for (int s = 128; s > 0; s >>= 1) { if (tid < s) red[tid] += red[tid + s]; __syncthreads(); }
    float inv = 1.f / red[0];
    __syncthreads();
    for (int j = tid; j < Ss; j += 256)
        td_sm[b * Ss + j] = tv[j] * inv;
}

// ---------------- attention: 16 q-rows/block, 512 threads, XCD-chunked remap ------
__device__ __forceinline__ int scix(int m, int j) {
    return m * 1024 + (j ^ (((m ^ (j >> 6)) & 7) << 2));
}

__global__ __launch_bounds__(512) void k_attn(const __bf16* __restrict__ qh,
                                              const __bf16* __restrict__ kh, const __bf16* __restrict__ kl,
                                              const __bf16* __restrict__ vt,
                                              const int* __restrict__ mask,
                                              const float* __restrict__ td_sm, const float* __restrict__ gammas,
                                              float* __restrict__ out) {
    __shared__ float sc[16 * 1024];      // 64 KB exactly
    int wg = blockIdx.x + 64 * blockIdx.y;
    int n  = (wg & 7) * 192 + (wg >> 3);
    int bx = n & 63, by = n >> 6;
    int i0 = bx * 16;
    int h = by % Hh, b = by / Hh;
    int tid = threadIdx.x;
    int w = tid >> 6, lane = tid & 63, quad = lane >> 4, l15 = lane & 15;
    int jw = w * 128;                     // this wave's j-range [jw, jw+128)

    // ---- phase 1: QK^T via MFMA: q_hi*(k_hi + k_lo) ----
    bf16x8 a_hi[2];
    {
        size_t qoff = (size_t)(b * Ss + i0 + l15) * AHc + h * Dd + quad * 8;
        a_hi[0] = *(const bf16x8*)(qh + qoff);
        a_hi[1] = *(const bf16x8*)(qh + qoff + 32);
    }
#pragma unroll 2
    for (int t = 0; t < 8; ++t) {
        int jt = jw + t * 16;
        size_t koff = (size_t)(b * Ss + jt + l15) * AHc + h * Dd + quad * 8;
        f32x4 acc = {0.f, 0.f, 0.f, 0.f};
#pragma unroll
        for (int kc = 0; kc < 2; ++kc) {
            bf16x8 khv = *(const bf16x8*)(kh + koff + kc * 32);
            bf16x8 klv = *(const bf16x8*)(kl + koff + kc * 32);
            acc = __builtin_amdgcn_mfma_f32_16x16x32_bf16(a_hi[kc], khv, acc, 0, 0, 0);
            acc = __builtin_amdgcn_mfma_f32_16x16x32_bf16(a_hi[kc], klv, acc, 0, 0, 0);
        }
#pragma unroll
        for (int r = 0; r < 4; ++r)
            sc[scix(quad * 4 + r, jt + l15)] = acc[r] * 0.125f;   // C: col=l15, row=quad*4+r
    }
    __syncthreads();

    // ---- phase 2: softmax -> cumsum -> decay -> softmax2, wave owns rows w*2, w*2+1 ----
    const int* mrow = mask + b * Ss;
    const float* tdrow = td_sm + b * Ss;
    float gamma = -log1pf(expf(gammas[h]));   // -softplus
    int jb = lane << 4;
    __attribute__((aligned(16))) int marr[16];
    {
        const int4* mp = (const int4*)(mrow + jb);
#pragma unroll
        for (int k = 0; k < 4; ++k) ((int4*)marr)[k] = mp[k];
    }
    __attribute__((aligned(16))) float tdv[16];
    {
        const float4* tp = (const float4*)(tdrow + jb);
#pragma unroll
        for (int k = 0; k < 4; ++k) ((float4*)tdv)[k] = tp[k];
    }

#pragma unroll
    for (int r4 = 0; r4 < 2; ++r4) {
        int m = w * 2 + r4;
        int i = i0 + m;
        __attribute__((aligned(16))) float s[16];
        float p[16];
#pragma unroll
        for (int g = 0; g < 4; ++g)
            *(f32x4*)(s + 4 * g) = *(const f32x4*)&sc[scix(m, jb + 4 * g)];
        float mx = -1e30f;
#pragma unroll
        for (int jj = 0; jj < 16; ++jj) mx = fmaxf(mx, marr[jj] ? s[jj] : -1e30f);
        mx = fmaxf(mx, __shfl_xor(mx, 1));  mx = fmaxf(mx, __shfl_xor(mx, 2));
        mx = fmaxf(mx, __shfl_xor(mx, 4));  mx = fmaxf(mx, __shfl_xor(mx, 8));
        mx = fmaxf(mx, __shfl_xor(mx, 16)); mx = fmaxf(mx, __shfl_xor(mx, 32));
#pragma unroll
        for (int jj = 0; jj < 16; ++jj) p[jj] = marr[jj] ? __expf(s[jj] - mx) : 0.f;
#pragma unroll
        for (int jj = 1; jj < 16; ++jj) p[jj] += p[jj - 1];
        float t = p[15];
        float incl = t;
#pragma unroll
        for (int dlt = 1; dlt < 64; dlt <<= 1) {
            float v = __shfl_up(incl, dlt);
            if (lane >= dlt) incl += v;
        }
        float off = incl - t;
        float tot = __shfl(incl, 63);
        float inv = 1.f / fmaxf(tot, 1e-30f);
        float mx2 = -1e30f;
#pragma unroll
        for (int jj = 0; jj < 16; ++jj) {
            int j = jb + jj;
            float cum = p[jj] + off;
            float pos = fabsf((float)(j - i));
            float ds = sqrtf(fmaxf((tot - cum) * inv * pos, 0.f));
            float te = fminf(fmaxf(__expf(ds * gamma), 1e-5f), 1e5f);
            float mult = te - ((j < i) ? tdv[jj] : 0.f);
            float s2 = marr[jj] ? s[jj] * mult : -1e8f;
            s[jj] = s2;
            mx2 = fmaxf(mx2, s2);
        }
        mx2 = fmaxf(mx2, __shfl_xor(mx2, 1));  mx2 = fmaxf(mx2, __shfl_xor(mx2, 2));
        mx2 = fmaxf(mx2, __shfl_xor(mx2, 4));  mx2 = fmaxf(mx2, __shfl_xor(mx2, 8));
        mx2 = fmaxf(mx2, __shfl_xor(mx2, 16)); mx2 = fmaxf(mx2, __shfl_xor(mx2, 32));
        float sm = 0.f;
#pragma unroll
        for (int jj = 0; jj < 16; ++jj) { s[jj] = __expf(s[jj] - mx2); sm += s[jj]; }
        sm += __shfl_xor(sm, 1);  sm += __shfl_xor(sm, 2);
        sm += __shfl_xor(sm, 4);  sm += __shfl_xor(sm, 8);
        sm += __shfl_xor(sm, 16); sm += __shfl_xor(sm, 32);
        float inv2 = 1.f / sm;
#pragma unroll
        for (int jj = 0; jj < 16; ++jj) s[jj] *= inv2;
#pragma unroll
        for (int g = 0; g < 4; ++g)
            *(f32x4*)&sc[scix(m, jb + 4 * g)] = *(const f32x4*)(s + 4 * g);
    }
    __syncthreads();

    // ---- phase 3: PV via MFMA: (p_hi + p_lo) * v_hi; V pre-transposed bf16 [d][j] ----
    f32x4 oacc[4] = {};
    const __bf16* vtb = vt + (size_t)(b * Hh + h) * Dd * Ss;
#pragma unroll
    for (int kc = 0; kc < 4; ++kc) {
        int j0 = jw + kc * 32 + quad * 8;        // this lane's 8 j indices (k = quad*8+e)
        __attribute__((aligned(16))) float x[8];
        *(f32x4*)x       = *(const f32x4*)&sc[scix(l15, j0)];
        *(f32x4*)(x + 4) = *(const f32x4*)&sc[scix(l15, j0 + 4)];
        bf16x8 p_hi, p_lo;
        split8r(x, p_hi, p_lo);
#pragma unroll
        for (int nt = 0; nt < 4; ++nt) {
            int d = nt * 16 + l15;
            bf16x8 vv = *(const bf16x8*)(vtb + (size_t)d * Ss + j0);
            oacc[nt] = __builtin_amdgcn_mfma_f32_16x16x32_bf16(p_hi, vv, oacc[nt], 0, 0, 0);
            oacc[nt] = __builtin_amdgcn_mfma_f32_16x16x32_bf16(p_lo, vv, oacc[nt], 0, 0, 0);
        }
    }
    __syncthreads();                      // all waves done reading sc before reuse
#pragma unroll
    for (int nt = 0; nt < 4; ++nt)
#pragma unroll
        for (int r = 0; r < 4; ++r)
            sc[w * 1024 + (quad * 4 + r) * 64 + nt * 16 + l15] = oacc[nt][r];
    __syncthreads();
#pragma unroll
    for (int e = 0; e < 2; ++e) {
        int idx = e * 512 + tid;
        int m = idx >> 6, dd = idx & 63;
        float v = 0.f;
#pragma unroll
        for (int ww = 0; ww < 8; ++ww) v += sc[ww * 1024 + idx];
        out[(size_t)(b * Ss + i0 + m) * (2 * AHc) + h * Dd + dd] = v;
    }
}

extern "C" void kernel_launch(void* const* d_in, const int* in_sizes, int n_in,
                              void* d_out, int out_size, void* d_ws, size_t ws_size,
                              hipStream_t stream) {
    const float* Q    = (const float*)d_in[0];
    const float* Kin  = (const float*)d_in[1];
    const float* V    = (const float*)d_in[2];
    const float* td   = (const float*)d_in[3];
    const int*   mask = (const int*)d_in[4];
    const float* Wq   = (const float*)d_in[5];
    const float* Wk   = (const float*)d_in[6];
    const float* Wv   = (const float*)d_in[7];
    const float* dww  = (const float*)d_in[8];
    const float* pww  = (const float*)d_in[9];
    const float* sepb = (const float*)d_in[10];
    const float* ckW  = (const float*)d_in[11];
    const float* ckb  = (const float*)d_in[12];
    const float* coW  = (const float*)d_in[13];
    const float* cob  = (const float*)d_in[14];
    const float* gam  = (const float*)d_in[15];
    float* out = (float*)d_out;
    float* ws = (float*)d_ws;

    float* mq    = ws;                              // z=0 C (f32)
    float* mks   = mq    + (size_t)MRr * AHc;       // z=1 slot -> kh/kl bf16
    float* mv    = mks   + (size_t)MRr * AHc;       // z=2
    float* co    = mv    + (size_t)MRr * AHc;       // z=3
    float* mkc   = co    + (size_t)MRr * AHc;       // z=4
    float* dwr   = mkc   + (size_t)MRr * AHc;       // MR*HID f32 region
    float* cksm  = dwr   + (size_t)MRr * HIDC;      // MR*H*KS
    float* tdsm  = cksm  + (size_t)MRr * Hh * KSc;  // B*S
    float* biasb = tdsm  + (size_t)Bb * Ss;         // 5*384

    // dwr region timeline: pre-gemm [dwbf | qbf] (bf16), post-gemm [qh | vt]
    __bf16* dwbf = (__bf16*)dwr;
    __bf16* qbf  = (__bf16*)(dwr + (size_t)MRr * HIDC / 2);
    __bf16* qh   = (__bf16*)dwr;
    __bf16* vt   = (__bf16*)(dwr + (size_t)MRr * HIDC / 2);
    // kh/kl live in the (otherwise dead) mk f32 slot
    __bf16* kh = (__bf16*)mks;
    __bf16* kl = kh + (size_t)MRr * AHc;

    // d_out scratch: Whi/Wlo (5.9 MB) + vbf (6.3 MB) — all dead after k_gemm5
    __bf16* Whi = (__bf16*)d_out;
    __bf16* Wlo = Whi + (size_t)5 * AHc * HIDC;
    __bf16* vbf = Wlo + (size_t)5 * AHc * HIDC;

    dim3 gt(AHc / 64, HIDC / 64, 4);    // 6 x 12 x 4
    k_wsplit_t<<<gt, 256, 0, stream>>>(Wq, Wk, Wv, coW, Whi, Wlo);
    k_wsplit_c<<<(AHc * HIDC / 8 + 255) / 256, 256, 0, stream>>>(pww, Whi, Wlo);
    k_absplit<<<(2 * MRr * HIDC / 8 + 255) / 256, 256, 0, stream>>>(Q, V, qbf, vbf);
    k_depthwise<<<(MRr * HIDC / 4 + 255) / 256, 256, 0, stream>>>(Kin, dww, dwbf);
    k_bias<<<(5 * AHc + 255) / 256, 256, 0, stream>>>(cob, sepb, biasb);

    dim3 gg(AHc / 128, MRr / 128, 5);   // 3 x 32 x 5
    k_gemm5<<<gg, 256, 0, stream>>>(qbf, Kin, vbf, dwbf, Whi, Wlo, biasb, mq, kh, kl);

    k_qkvsplit<<<(MRr * AHc / 8 + 255) / 256, 256, 0, stream>>>(mq, qh);
    k_vtrans<<<dim3(Ss / 64, Bb * Hh), 256, 0, stream>>>(mv, vt);
    k_ck<<<MRr, 64, 0, stream>>>(mkc, mq, ckW, ckb, cksm);
    k_convout<<<(MRr * AHc / 4 + 255) / 256, 256, 0, stream>>>(co, cksm, out);
    k_td<<<Bb, 256, 0, stream>>>(td, mask, tdsm);

    dim3 ga(Ss / 16, Bb * Hh);          // 64 x 24
    k_attn<<<ga, 512, 0, stream>>>(qh, kh, kl, vt, mask, tdsm, gam, out);
}

// Round 7
// 281.706 us; speedup vs baseline: 1.1423x; 1.0770x over previous
//
#include <hip/hip_runtime.h>
#include <hip/hip_bf16.h>

#define HIDC 768
#define Hh   6
#define Dd   64
#define AHc  384
#define KSc  9
#define PADc 4
#define Bb   4
#define Ss   1024
#define MRr  (Bb * Ss)          // 4096

typedef __attribute__((ext_vector_type(8))) __bf16 bf16x8;
typedef __attribute__((ext_vector_type(4))) __bf16 bf16x4;
typedef __attribute__((ext_vector_type(4))) float  f32x4;

// async global->LDS, 16 bytes per lane; dest = wave-uniform base + lane*16
__device__ __forceinline__ void gl_lds16(const void* g, void* l) {
    __builtin_amdgcn_global_load_lds(
        (const __attribute__((address_space(1))) void*)g,
        (__attribute__((address_space(3))) void*)l, 16, 0, 0);
}

// split 8 consecutive f32 into hi/lo bf16 fragments
__device__ __forceinline__ void split8(const float* p, bf16x8& hi, bf16x8& lo) {
    float4 x0 = *(const float4*)p;
    float4 x1 = *(const float4*)(p + 4);
    float xs[8] = {x0.x, x0.y, x0.z, x0.w, x1.x, x1.y, x1.z, x1.w};
#pragma unroll
    for (int e = 0; e < 8; ++e) {
        __bf16 hv = (__bf16)xs[e];
        hi[e] = hv;
        lo[e] = (__bf16)(xs[e] - (float)hv);
    }
}

__device__ __forceinline__ void split8r(const float* xs, bf16x8& hi, bf16x8& lo) {
#pragma unroll
    for (int e = 0; e < 8; ++e) {
        __bf16 hv = (__bf16)xs[e];
        hi[e] = hv;
        lo[e] = (__bf16)(xs[e] - (float)hv);
    }
}

// convert 8 consecutive f32 to bf16 (hi only)
__device__ __forceinline__ bf16x8 cvt8(const float* p) {
    float4 x0 = *(const float4*)p;
    float4 x1 = *(const float4*)(p + 4);
    float xs[8] = {x0.x, x0.y, x0.z, x0.w, x1.x, x1.y, x1.z, x1.w};
    bf16x8 h;
#pragma unroll
    for (int e = 0; e < 8; ++e) h[e] = (__bf16)xs[e];
    return h;
}

// ---------------- fused: depthwise conv -> dwbf  +  Q/V pre-convert ----------------
// blocks [0, 3072): depthwise; blocks [3072, 6144): absplit
__global__ void k_dwab(const float* __restrict__ Kin, const float* __restrict__ dww,
                       const float* __restrict__ Q, const float* __restrict__ V,
                       __bf16* __restrict__ dwbf,
                       __bf16* __restrict__ qbf, __bf16* __restrict__ vbf) {
    int bid = blockIdx.x;
    if (bid < 3072) {
        int idx = bid * 256 + threadIdx.x;             // over B*S*HID/4
        int c4 = idx % (HIDC / 4);
        int s  = (idx / (HIDC / 4)) % Ss;
        int b  = idx / ((HIDC / 4) * Ss);
        int c  = c4 * 4;
        float wv[4][KSc];
#pragma unroll
        for (int j = 0; j < 4; ++j)
#pragma unroll
            for (int k = 0; k < KSc; ++k) wv[j][k] = dww[(c + j) * KSc + k];
        float4 acc = {0.f, 0.f, 0.f, 0.f};
#pragma unroll
        for (int k = 0; k < KSc; ++k) {
            int sp = s + k - PADc;
            if (sp >= 0 && sp < Ss) {
                float4 v = *(const float4*)&Kin[(size_t)(b * Ss + sp) * HIDC + c];
                acc.x += v.x * wv[0][k]; acc.y += v.y * wv[1][k];
                acc.z += v.z * wv[2][k]; acc.w += v.w * wv[3][k];
            }
        }
        bf16x4 o = {(__bf16)acc.x, (__bf16)acc.y, (__bf16)acc.z, (__bf16)acc.w};
        *(bf16x4*)(dwbf + (size_t)idx * 4) = o;
    } else {
        const int n8 = MRr * HIDC / 8;
        int idx = (bid - 3072) * 256 + threadIdx.x;    // over 2 * MR*HID/8
        if (idx < n8) {
            *(bf16x8*)(qbf + (size_t)idx * 8) = cvt8(Q + (size_t)idx * 8);
        } else {
            int i = idx - n8;
            *(bf16x8*)(vbf + (size_t)i * 8) = cvt8(V + (size_t)i * 8);
        }
    }
}

// ---------------- transposed weight split (z=0..3): LDS-tiled ----------------
__global__ __launch_bounds__(256) void k_wsplit_t(const float* __restrict__ Wq, const float* __restrict__ Wk,
                                                  const float* __restrict__ Wv, const float* __restrict__ coW,
                                                  __bf16* __restrict__ Whi, __bf16* __restrict__ Wlo) {
    int z = blockIdx.z;
    const float* src = (z == 0) ? Wq : (z == 1) ? Wk : (z == 2) ? Wv : coW;
    int n0 = blockIdx.x * 64, k0 = blockIdx.y * 64;
    int tid = threadIdx.x;
    int r = tid >> 2, cq = tid & 3;
    __shared__ float tile[64][65];      // tile[k_local][n_local]
#pragma unroll
    for (int e = 0; e < 4; ++e) {
        float4 v = *(const float4*)&src[(size_t)(k0 + r) * AHc + n0 + cq * 16 + e * 4];
        tile[r][cq * 16 + e * 4 + 0] = v.x;
        tile[r][cq * 16 + e * 4 + 1] = v.y;
        tile[r][cq * 16 + e * 4 + 2] = v.z;
        tile[r][cq * 16 + e * 4 + 3] = v.w;
    }
    __syncthreads();
    float x[16];
#pragma unroll
    for (int e = 0; e < 16; ++e) x[e] = tile[cq * 16 + e][r];
    bf16x8 h0, l0, h1, l1;
    split8r(x, h0, l0);
    split8r(x + 8, h1, l1);
    size_t dst = ((size_t)(z * AHc + n0 + r)) * HIDC + k0 + cq * 16;
    *(bf16x8*)(Whi + dst)     = h0;
    *(bf16x8*)(Whi + dst + 8) = h1;
    *(bf16x8*)(Wlo + dst)     = l0;
    *(bf16x8*)(Wlo + dst + 8) = l1;
}

// ---------------- fused misc: pw_w split + bias buffer + td softmax ----------------
// blocks [0,144): wsplit_c; [144,152): bias; [152,156): td
__global__ __launch_bounds__(256) void k_misc(const float* __restrict__ pww,
                                              const float* __restrict__ cob, const float* __restrict__ sepb,
                                              const float* __restrict__ td, const int* __restrict__ mask,
                                              __bf16* __restrict__ Whi, __bf16* __restrict__ Wlo,
                                              float* __restrict__ biasb, float* __restrict__ td_sm) {
    int bid = blockIdx.x;
    int tid = threadIdx.x;
    if (bid < 144) {
        int idx = bid * 256 + tid;                     // over AHc*HIDC/8
        bf16x8 hi, lo;
        split8(pww + (size_t)idx * 8, hi, lo);
        size_t dst = (size_t)4 * AHc * HIDC + (size_t)idx * 8;
        *(bf16x8*)(Whi + dst) = hi;
        *(bf16x8*)(Wlo + dst) = lo;
        return;
    }
    if (bid < 152) {
        int idx = (bid - 144) * 256 + tid;
        if (idx < 5 * AHc) {
            int z = idx / AHc, n = idx % AHc;
            biasb[idx] = (z == 3) ? cob[n] : (z == 4) ? sepb[n] : 0.f;
        }
        return;
    }
    // td softmax, one block per batch
    int b = bid - 152;
    __shared__ float red[256];
    __shared__ float tv[Ss];
    float ls = 0.f;
    for (int j = tid; j < Ss; j += 256) {
        float v = td[b * Ss + j];
        tv[j] = v;
        ls += v * v;
    }
    red[tid] = ls; __syncthreads();
    for (int s = 128; s > 0; s >>= 1) { if (tid < s) red[tid] += red[tid + s]; __syncthreads(); }
    float norm = fmaxf(sqrtf(red[0]), 1e-12f);
    __syncthreads();
    float lm = -3e38f;
    for (int j = tid; j < Ss; j += 256) {
        float v = mask[b * Ss + j] ? tv[j] / norm : -1e4f;
        tv[j] = v;
        lm = fmaxf(lm, v);
    }
    red[tid] = lm; __syncthreads();
    for (int s = 128; s > 0; s >>= 1) { if (tid < s) red[tid] = fmaxf(red[tid], red[tid + s]); __syncthreads(); }
    float m = red[0]; __syncthreads();
    float lsum = 0.f;
    for (int j = tid; j < Ss; j += 256) {
        float e = expf(tv[j] - m);
        tv[j] = e;
        lsum += e;
    }
    red[tid] = lsum; __syncthreads();
    for (int s = 128; s > 0; s >>= 1) { if (tid < s) red[tid] += red[tid + s]; __syncthreads(); }
    float inv = 1.f / red[0];
    __syncthreads();
    for (int j = tid; j < Ss; j += 256)
        td_sm[b * Ss + j] = tv[j] * inv;
}

// ---------------- batched MFMA GEMM (2-term: ah*(bh+bl)) ----------------
// A (bf16 pre-split, except z=1) and B both staged via global_load_lds into linear
// [128][32] LDS with granule XOR swizzle: slot s of row r holds global granule
// s ^ (r & 3). Read granule q of row r at slot q ^ (r&3).
// Fused epilogues: z=0 -> mq f32 + qh bf16; z=1 -> kh/kl bf16; z=2 -> vt bf16
// transposed (no f32 C at all); z=3/4 -> co/mkc f32 + bias.
__global__ __launch_bounds__(256) void k_gemm5(
        const __bf16* __restrict__ qbf, const float* __restrict__ Kin,
        const __bf16* __restrict__ vbf, const __bf16* __restrict__ dwbf,
        const __bf16* __restrict__ Whi, const __bf16* __restrict__ Wlo,
        const float* __restrict__ biasb, float* __restrict__ Call,
        __bf16* __restrict__ kh, __bf16* __restrict__ kl,
        __bf16* __restrict__ qh, __bf16* __restrict__ vt) {
    __shared__ __attribute__((aligned(16))) __bf16 As [128 * 32];
    __shared__ __attribute__((aligned(16))) __bf16 BsH[128 * 32];
    __shared__ __attribute__((aligned(16))) __bf16 BsL[128 * 32];

    int wg = blockIdx.x + 3 * (blockIdx.y + 32 * blockIdx.z);   // 0..479
    int n2 = (wg & 7) * 60 + (wg >> 3);                         // bijective (480%8==0)
    int bxx = n2 % 3, byy = (n2 / 3) % 32, z = n2 / 96;

    int m0 = byy * 128, n0 = bxx * 128;
    int tid = threadIdx.x;
    int wave = tid >> 6, lane = tid & 63, quad = lane >> 4, l15 = lane & 15;

    int lrow = lane >> 2;                                // 0..15 within instr
    int lswz = 8 * ((lane & 3) ^ (lrow & 3));            // swizzled src granule offset

    // B staging (gl_lds): instr p = wave*2+q covers rows p*16..p*16+15
    int brow = wave * 32 + lrow;
    const __bf16* BhG0 = Whi + ((size_t)(z * AHc + n0 + brow)) * HIDC + lswz;
    const __bf16* BhG1 = BhG0 + (size_t)16 * HIDC;
    const __bf16* BlG0 = Wlo + ((size_t)(z * AHc + n0 + brow)) * HIDC + lswz;
    const __bf16* BlG1 = BlG0 + (size_t)16 * HIDC;
    __bf16* BhL0 = BsH + (wave * 2 + 0) * 512;
    __bf16* BhL1 = BsH + (wave * 2 + 1) * 512;
    __bf16* BlL0 = BsL + (wave * 2 + 0) * 512;
    __bf16* BlL1 = BsL + (wave * 2 + 1) * 512;

    // A staging (gl_lds path, z != 1)
    const __bf16* Abf = (z == 0) ? qbf : (z == 4) ? dwbf : vbf;
    const __bf16* AG0 = Abf + ((size_t)(m0 + wave * 32 + lrow)) * HIDC + lswz;
    const __bf16* AG1 = AG0 + (size_t)16 * HIDC;
    __bf16* AL0 = As + (wave * 2 + 0) * 512;
    __bf16* AL1 = As + (wave * 2 + 1) * 512;

    // A staging (f32 path, z == 1): swizzled ds_write of cvt'd granule pairs
    int sr = tid >> 1;
    int sk = (tid & 1) * 16;
    const float* Arow = Kin + (size_t)(m0 + sr) * HIDC + sk;
    int g0 = sk >> 3;                                    // 0 or 2
    int d0 = sr * 32 + ((g0       ^ (sr & 3)) * 8);
    int d1 = sr * 32 + (((g0 + 1) ^ (sr & 3)) * 8);

    int swz = (quad ^ (l15 & 3)) * 8;                    // swizzled read offset
    f32x4 acc[4][4] = {};

    for (int k0 = 0; k0 < HIDC; k0 += 32) {
        if (z == 1) {
            const float* ap = Arow + k0;
            *(bf16x8*)&As[d0] = cvt8(ap);
            *(bf16x8*)&As[d1] = cvt8(ap + 8);
        } else {
            gl_lds16(AG0 + k0, AL0);
            gl_lds16(AG1 + k0, AL1);
        }
        gl_lds16(BhG0 + k0, BhL0);
        gl_lds16(BhG1 + k0, BhL1);
        gl_lds16(BlG0 + k0, BlL0);
        gl_lds16(BlG1 + k0, BlL1);
        __syncthreads();

        int mrow = (wave >> 1) * 64 + l15;
        int nrow = (wave & 1) * 64 + l15;
        bf16x8 ah[4], bh[4], bl[4];
#pragma unroll
        for (int mt = 0; mt < 4; ++mt)
            ah[mt] = *(bf16x8*)&As[(mrow + mt * 16) * 32 + swz];
#pragma unroll
        for (int nt = 0; nt < 4; ++nt) {
            bh[nt] = *(bf16x8*)&BsH[(nrow + nt * 16) * 32 + swz];
            bl[nt] = *(bf16x8*)&BsL[(nrow + nt * 16) * 32 + swz];
        }
#pragma unroll
        for (int mt = 0; mt < 4; ++mt)
#pragma unroll
            for (int nt = 0; nt < 4; ++nt) {
                acc[mt][nt] = __builtin_amdgcn_mfma_f32_16x16x32_bf16(ah[mt], bh[nt], acc[mt][nt], 0, 0, 0);
                acc[mt][nt] = __builtin_amdgcn_mfma_f32_16x16x32_bf16(ah[mt], bl[nt], acc[mt][nt], 0, 0, 0);
            }
        __syncthreads();
    }

    if (z == 1) {
        // zero bias; emit kh/kl bf16 directly (K used only by attention)
#pragma unroll
        for (int nt = 0; nt < 4; ++nt) {
            int n = n0 + (wave & 1) * 64 + nt * 16 + l15;
#pragma unroll
            for (int mt = 0; mt < 4; ++mt) {
#pragma unroll
                for (int r = 0; r < 4; ++r) {
                    int m = m0 + (wave >> 1) * 64 + mt * 16 + quad * 4 + r;
                    float v = acc[mt][nt][r];
                    __bf16 hv = (__bf16)v;
                    kh[(size_t)m * AHc + n] = hv;
                    kl[(size_t)m * AHc + n] = (__bf16)(v - (float)hv);
                }
            }
        }
    } else if (z == 2) {
        // zero bias; emit vt bf16 transposed directly: vt[(b*H+h)*D+d][s]
        int b = m0 >> 10;
#pragma unroll
        for (int nt = 0; nt < 4; ++nt) {
            int n = (wave & 1) * 64 + nt * 16 + l15;     // 0..127 within n0 tile
            int gn = n0 + n;                             // global col = h*64+d
            int h = gn >> 6, d = gn & 63;
#pragma unroll
            for (int mt = 0; mt < 4; ++mt) {
                int m = m0 + (wave >> 1) * 64 + mt * 16 + quad * 4;
                int s = m & (Ss - 1);
                bf16x4 o = {(__bf16)acc[mt][nt][0], (__bf16)acc[mt][nt][1],
                            (__bf16)acc[mt][nt][2], (__bf16)acc[mt][nt][3]};
                *(bf16x4*)&vt[((size_t)((b * Hh + h) * Dd + d)) * Ss + s] = o;
            }
        }
    } else if (z == 0) {
        // zero bias; write mq f32 (k_ck) + qh bf16 (attention)
#pragma unroll
        for (int nt = 0; nt < 4; ++nt) {
            int n = n0 + (wave & 1) * 64 + nt * 16 + l15;
#pragma unroll
            for (int mt = 0; mt < 4; ++mt) {
#pragma unroll
                for (int r = 0; r < 4; ++r) {
                    int m = m0 + (wave >> 1) * 64 + mt * 16 + quad * 4 + r;
                    float v = acc[mt][nt][r];
                    Call[(size_t)m * AHc + n] = v;
                    qh[(size_t)m * AHc + n] = (__bf16)v;
                }
            }
        }
    } else {
        float* Cz = Call + (size_t)z * MRr * AHc;
        const float* bz = biasb + z * AHc;
#pragma unroll
        for (int nt = 0; nt < 4; ++nt) {
            int n = n0 + (wave & 1) * 64 + nt * 16 + l15;
            float bias = bz[n];
#pragma unroll
            for (int mt = 0; mt < 4; ++mt) {
#pragma unroll
                for (int r = 0; r < 4; ++r) {
                    int m = m0 + (wave >> 1) * 64 + mt * 16 + quad * 4 + r;
                    Cz[(size_t)m * AHc + n] = acc[mt][nt][r] + bias;
                }
            }
        }
    }
}

// ---------------- conv_attn -> ck linear -> per-head softmax over KS ----------------
__global__ __launch_bounds__(64) void k_ck(const float* __restrict__ mkc, const float* __restrict__ mq,
                                           const float* __restrict__ ckW, const float* __restrict__ ckb,
                                           float* __restrict__ ck_sm) {
    int row = blockIdx.x;            // b*S + s
    int tid = threadIdx.x;
    __shared__ float ca[AHc];
    __shared__ float ckv[Hh * KSc];
    for (int o = tid; o < AHc; o += 64)
        ca[o] = mkc[row * AHc + o] * mq[row * AHc + o];
    __syncthreads();
    if (tid < Hh * KSc) {
        float acc = ckb[tid];
        for (int o = 0; o < AHc; ++o)
            acc += ca[o] * ckW[o * (Hh * KSc) + tid];
        ckv[tid] = acc;
    }
    __syncthreads();
    if (tid < Hh) {
        float m = -3e38f;
#pragma unroll
        for (int k = 0; k < KSc; ++k) m = fmaxf(m, ckv[tid * KSc + k]);
        float e[KSc];
        float s = 0.f;
#pragma unroll
        for (int k = 0; k < KSc; ++k) { e[k] = expf(ckv[tid * KSc + k] - m); s += e[k]; }
        float inv = 1.f / s;
#pragma unroll
        for (int k = 0; k < KSc; ++k) ck_sm[(row * Hh + tid) * KSc + k] = e[k] * inv;
    }
}

// ---------------- dynamic conv output (float4) -> out[.., AH + h*D + d] ----------------
__global__ void k_convout(const float* __restrict__ co, const float* __restrict__ ck_sm,
                          float* __restrict__ out) {
    int idx = blockIdx.x * 256 + threadIdx.x;       // over B*S*AH/4
    if (idx >= Bb * Ss * AHc / 4) return;
    int d4 = idx & 15;
    int h  = (idx >> 4) % Hh;
    int s  = (idx / (AHc / 4)) % Ss;
    int b  = idx / ((AHc / 4) * Ss);
    int row = b * Ss + s;
    const float* ck = ck_sm + (size_t)(row * Hh + h) * KSc;
    float4 acc = {0.f, 0.f, 0.f, 0.f};
#pragma unroll
    for (int k = 0; k < KSc; ++k) {
        int sp = s + k - PADc;
        if (sp >= 0 && sp < Ss) {
            float4 v = *(const float4*)&co[(size_t)(b * Ss + sp) * AHc + h * Dd + d4 * 4];
            float wv = ck[k];
            acc.x += wv * v.x; acc.y += wv * v.y; acc.z += wv * v.z; acc.w += wv * v.w;
        }
    }
    *(float4*)&out[(size_t)row * (2 * AHc) + AHc + h * Dd + d4 * 4] = acc;
}

// ---------------- attention: 16 q-rows/block, 512 threads, XCD-chunked remap ------
__device__ __forceinline__ int scix(int m, int j) {
    return m * 1024 + (j ^ (((m ^ (j >> 6)) & 7) << 2));
}

__global__ __launch_bounds__(512) void k_attn(const __bf16* __restrict__ qh,
                                              const __bf16* __restrict__ kh, const __bf16* __restrict__ kl,
                                              const __bf16* __restrict__ vt,
                                              const int* __restrict__ mask,
                                              const float* __restrict__ td_sm, const float* __restrict__ gammas,
                                              float* __restrict__ out) {
    __shared__ float sc[16 * 1024];      // 64 KB exactly
    int wg = blockIdx.x + 64 * blockIdx.y;
    int n  = (wg & 7) * 192 + (wg >> 3);
    int bx = n & 63, by = n >> 6;
    int i0 = bx * 16;
    int h = by % Hh, b = by / Hh;
    int tid = threadIdx.x;
    int w = tid >> 6, lane = tid & 63, quad = lane >> 4, l15 = lane & 15;
    int jw = w * 128;                     // this wave's j-range [jw, jw+128)

    // ---- phase 1: QK^T via MFMA: q_hi*(k_hi + k_lo) ----
    bf16x8 a_hi[2];
    {
        size_t qoff = (size_t)(b * Ss + i0 + l15) * AHc + h * Dd + quad * 8;
        a_hi[0] = *(const bf16x8*)(qh + qoff);
        a_hi[1] = *(const bf16x8*)(qh + qoff + 32);
    }
#pragma unroll 2
    for (int t = 0; t < 8; ++t) {
        int jt = jw + t * 16;
        size_t koff = (size_t)(b * Ss + jt + l15) * AHc + h * Dd + quad * 8;
        f32x4 acc = {0.f, 0.f, 0.f, 0.f};
#pragma unroll
        for (int kc = 0; kc < 2; ++kc) {
            bf16x8 khv = *(const bf16x8*)(kh + koff + kc * 32);
            bf16x8 klv = *(const bf16x8*)(kl + koff + kc * 32);
            acc = __builtin_amdgcn_mfma_f32_16x16x32_bf16(a_hi[kc], khv, acc, 0, 0, 0);
            acc = __builtin_amdgcn_mfma_f32_16x16x32_bf16(a_hi[kc], klv, acc, 0, 0, 0);
        }
#pragma unroll
        for (int r = 0; r < 4; ++r)
            sc[scix(quad * 4 + r, jt + l15)] = acc[r] * 0.125f;   // C: col=l15, row=quad*4+r
    }
    __syncthreads();

    // ---- phase 2: softmax -> cumsum -> decay -> softmax2, wave owns rows w*2, w*2+1 ----
    const int* mrow = mask + b * Ss;
    const float* tdrow = td_sm + b * Ss;
    float gamma = -log1pf(expf(gammas[h]));   // -softplus
    int jb = lane << 4;
    __attribute__((aligned(16))) int marr[16];
    {
        const int4* mp = (const int4*)(mrow + jb);
#pragma unroll
        for (int k = 0; k < 4; ++k) ((int4*)marr)[k] = mp[k];
    }
    __attribute__((aligned(16))) float tdv[16];
    {
        const float4* tp = (const float4*)(tdrow + jb);
#pragma unroll
        for (int k = 0; k < 4; ++k) ((float4*)tdv)[k] = tp[k];
    }

#pragma unroll
    for (int r4 = 0; r4 < 2; ++r4) {
        int m = w * 2 + r4;
        int i = i0 + m;
        __attribute__((aligned(16))) float s[16];
        float p[16];
#pragma unroll
        for (int g = 0; g < 4; ++g)
            *(f32x4*)(s + 4 * g) = *(const f32x4*)&sc[scix(m, jb + 4 * g)];
        float mx = -1e30f;
#pragma unroll
        for (int jj = 0; jj < 16; ++jj) mx = fmaxf(mx, marr[jj] ? s[jj] : -1e30f);
        mx = fmaxf(mx, __shfl_xor(mx, 1));  mx = fmaxf(mx, __shfl_xor(mx, 2));
        mx = fmaxf(mx, __shfl_xor(mx, 4));  mx = fmaxf(mx, __shfl_xor(mx, 8));
        mx = fmaxf(mx, __shfl_xor(mx, 16)); mx = fmaxf(mx, __shfl_xor(mx, 32));
#pragma unroll
        for (int jj = 0; jj < 16; ++jj) p[jj] = marr[jj] ? __expf(s[jj] - mx) : 0.f;
#pragma unroll
        for (int jj = 1; jj < 16; ++jj) p[jj] += p[jj - 1];
        float t = p[15];
        float incl = t;
#pragma unroll
        for (int dlt = 1; dlt < 64; dlt <<= 1) {
            float v = __shfl_up(incl, dlt);
            if (lane >= dlt) incl += v;
        }
        float off = incl - t;
        float tot = __shfl(incl, 63);
        float inv = 1.f / fmaxf(tot, 1e-30f);
        float mx2 = -1e30f;
#pragma unroll
        for (int jj = 0; jj < 16; ++jj) {
            int j = jb + jj;
            float cum = p[jj] + off;
            float pos = fabsf((float)(j - i));
            float ds = sqrtf(fmaxf((tot - cum) * inv * pos, 0.f));
            float te = fminf(fmaxf(__expf(ds * gamma), 1e-5f), 1e5f);
            float mult = te - ((j < i) ? tdv[jj] : 0.f);
            float s2 = marr[jj] ? s[jj] * mult : -1e8f;
            s[jj] = s2;
            mx2 = fmaxf(mx2, s2);
        }
        mx2 = fmaxf(mx2, __shfl_xor(mx2, 1));  mx2 = fmaxf(mx2, __shfl_xor(mx2, 2));
        mx2 = fmaxf(mx2, __shfl_xor(mx2, 4));  mx2 = fmaxf(mx2, __shfl_xor(mx2, 8));
        mx2 = fmaxf(mx2, __shfl_xor(mx2, 16)); mx2 = fmaxf(mx2, __shfl_xor(mx2, 32));
        float sm = 0.f;
#pragma unroll
        for (int jj = 0; jj < 16; ++jj) { s[jj] = __expf(s[jj] - mx2); sm += s[jj]; }
        sm += __shfl_xor(sm, 1);  sm += __shfl_xor(sm, 2);
        sm += __shfl_xor(sm, 4);  sm += __shfl_xor(sm, 8);
        sm += __shfl_xor(sm, 16); sm += __shfl_xor(sm, 32);
        float inv2 = 1.f / sm;
#pragma unroll
        for (int jj = 0; jj < 16; ++jj) s[jj] *= inv2;
#pragma unroll
        for (int g = 0; g < 4; ++g)
            *(f32x4*)&sc[scix(m, jb + 4 * g)] = *(const f32x4*)(s + 4 * g);
    }
    __syncthreads();

    // ---- phase 3: PV via MFMA: (p_hi + p_lo) * v_hi; V pre-transposed bf16 [d][j] ----
    f32x4 oacc[4] = {};
    const __bf16* vtb = vt + (size_t)(b * Hh + h) * Dd * Ss;
#pragma unroll
    for (int kc = 0; kc < 4; ++kc) {
        int j0 = jw + kc * 32 + quad * 8;        // this lane's 8 j indices (k = quad*8+e)
        __attribute__((aligned(16))) float x[8];
        *(f32x4*)x       = *(const f32x4*)&sc[scix(l15, j0)];
        *(f32x4*)(x + 4) = *(const f32x4*)&sc[scix(l15, j0 + 4)];
        bf16x8 p_hi, p_lo;
        split8r(x, p_hi, p_lo);
#pragma unroll
        for (int nt = 0; nt < 4; ++nt) {
            int d = nt * 16 + l15;
            bf16x8 vv = *(const bf16x8*)(vtb + (size_t)d * Ss + j0);
            oacc[nt] = __builtin_amdgcn_mfma_f32_16x16x32_bf16(p_hi, vv, oacc[nt], 0, 0, 0);
            oacc[nt] = __builtin_amdgcn_mfma_f32_16x16x32_bf16(p_lo, vv, oacc[nt], 0, 0, 0);
        }
    }
    __syncthreads();                      // all waves done reading sc before reuse
#pragma unroll
    for (int nt = 0; nt < 4; ++nt)
#pragma unroll
        for (int r = 0; r < 4; ++r)
            sc[w * 1024 + (quad * 4 + r) * 64 + nt * 16 + l15] = oacc[nt][r];
    __syncthreads();
#pragma unroll
    for (int e = 0; e < 2; ++e) {
        int idx = e * 512 + tid;
        int m = idx >> 6, dd = idx & 63;
        float v = 0.f;
#pragma unroll
        for (int ww = 0; ww < 8; ++ww) v += sc[ww * 1024 + idx];
        out[(size_t)(b * Ss + i0 + m) * (2 * AHc) + h * Dd + dd] = v;
    }
}

extern "C" void kernel_launch(void* const* d_in, const int* in_sizes, int n_in,
                              void* d_out, int out_size, void* d_ws, size_t ws_size,
                              hipStream_t stream) {
    const float* Q    = (const float*)d_in[0];
    const float* Kin  = (const float*)d_in[1];
    const float* V    = (const float*)d_in[2];
    const float* td   = (const float*)d_in[3];
    const int*   mask = (const int*)d_in[4];
    const float* Wq   = (const float*)d_in[5];
    const float* Wk   = (const float*)d_in[6];
    const float* Wv   = (const float*)d_in[7];
    const float* dww  = (const float*)d_in[8];
    const float* pww  = (const float*)d_in[9];
    const float* sepb = (const float*)d_in[10];
    const float* ckW  = (const float*)d_in[11];
    const float* ckb  = (const float*)d_in[12];
    const float* coW  = (const float*)d_in[13];
    const float* cob  = (const float*)d_in[14];
    const float* gam  = (const float*)d_in[15];
    float* out = (float*)d_out;
    float* ws = (float*)d_ws;

    float* mq    = ws;                              // z=0 C (f32)
    float* mks   = mq    + (size_t)MRr * AHc;       // z=1 slot -> kh/kl bf16
    float* mvs   = mks   + (size_t)MRr * AHc;       // z=2 slot -> vt + qh bf16
    float* co    = mvs   + (size_t)MRr * AHc;       // z=3
    float* mkc   = co    + (size_t)MRr * AHc;       // z=4
    float* dwr   = mkc   + (size_t)MRr * AHc;       // MR*HID f32 region
    float* cksm  = dwr   + (size_t)MRr * HIDC;      // MR*H*KS
    float* tdsm  = cksm  + (size_t)MRr * Hh * KSc;  // B*S
    float* biasb = tdsm  + (size_t)Bb * Ss;         // 5*384

    // dwr region: pre-gemm staging [dwbf | qbf] bf16 (dead after k_gemm5)
    __bf16* dwbf = (__bf16*)dwr;
    __bf16* qbf  = (__bf16*)(dwr + (size_t)MRr * HIDC / 2);
    // attention operands live in dedicated ws slots (no aliasing with gemm inputs):
    __bf16* kh = (__bf16*)mks;                      // z=1 epilogue output
    __bf16* kl = kh + (size_t)MRr * AHc;
    __bf16* vt = (__bf16*)mvs;                      // z=2 epilogue output (transposed V)
    __bf16* qh = vt + (size_t)MRr * AHc;            // z=0 epilogue output

    // d_out scratch: Whi/Wlo (5.9 MB) + vbf (6.3 MB) — dead after k_gemm5
    __bf16* Whi = (__bf16*)d_out;
    __bf16* Wlo = Whi + (size_t)5 * AHc * HIDC;
    __bf16* vbf = Wlo + (size_t)5 * AHc * HIDC;

    dim3 gt(AHc / 64, HIDC / 64, 4);    // 6 x 12 x 4
    k_wsplit_t<<<gt, 256, 0, stream>>>(Wq, Wk, Wv, coW, Whi, Wlo);
    k_misc<<<156, 256, 0, stream>>>(pww, cob, sepb, td, mask, Whi, Wlo, biasb, tdsm);
    k_dwab<<<6144, 256, 0, stream>>>(Kin, dww, Q, V, dwbf, qbf, vbf);

    dim3 gg(AHc / 128, MRr / 128, 5);   // 3 x 32 x 5
    k_gemm5<<<gg, 256, 0, stream>>>(qbf, Kin, vbf, dwbf, Whi, Wlo, biasb, mq, kh, kl, qh, vt);

    k_ck<<<MRr, 64, 0, stream>>>(mkc, mq, ckW, ckb, cksm);
    k_convout<<<(MRr * AHc / 4 + 255) / 256, 256, 0, stream>>>(co, cksm, out);

    dim3 ga(Ss / 16, Bb * Hh);          // 64 x 24
    k_attn<<<ga, 512, 0, stream>>>(qh, kh, kl, vt, mask, tdsm, gam, out);
}

// Round 8
// 272.597 us; speedup vs baseline: 1.1805x; 1.0334x over previous
//
#include <hip/hip_runtime.h>
#include <hip/hip_bf16.h>

#define HIDC 768
#define Hh   6
#define Dd   64
#define AHc  384
#define KSc  9
#define PADc 4
#define Bb   4
#define Ss   1024
#define MRr  (Bb * Ss)          // 4096

typedef __attribute__((ext_vector_type(8))) __bf16 bf16x8;
typedef __attribute__((ext_vector_type(4))) __bf16 bf16x4;
typedef __attribute__((ext_vector_type(4))) float  f32x4;

// async global->LDS, 16 bytes per lane; dest = wave-uniform base + lane*16
__device__ __forceinline__ void gl_lds16(const void* g, void* l) {
    __builtin_amdgcn_global_load_lds(
        (const __attribute__((address_space(1))) void*)g,
        (__attribute__((address_space(3))) void*)l, 16, 0, 0);
}

// split 8 consecutive f32 into hi/lo bf16 fragments
__device__ __forceinline__ void split8(const float* p, bf16x8& hi, bf16x8& lo) {
    float4 x0 = *(const float4*)p;
    float4 x1 = *(const float4*)(p + 4);
    float xs[8] = {x0.x, x0.y, x0.z, x0.w, x1.x, x1.y, x1.z, x1.w};
#pragma unroll
    for (int e = 0; e < 8; ++e) {
        __bf16 hv = (__bf16)xs[e];
        hi[e] = hv;
        lo[e] = (__bf16)(xs[e] - (float)hv);
    }
}

__device__ __forceinline__ void split8r(const float* xs, bf16x8& hi, bf16x8& lo) {
#pragma unroll
    for (int e = 0; e < 8; ++e) {
        __bf16 hv = (__bf16)xs[e];
        hi[e] = hv;
        lo[e] = (__bf16)(xs[e] - (float)hv);
    }
}

// convert 8 consecutive f32 to bf16 (hi only)
__device__ __forceinline__ bf16x8 cvt8(const float* p) {
    float4 x0 = *(const float4*)p;
    float4 x1 = *(const float4*)(p + 4);
    float xs[8] = {x0.x, x0.y, x0.z, x0.w, x1.x, x1.y, x1.z, x1.w};
    bf16x8 h;
#pragma unroll
    for (int e = 0; e < 8; ++e) h[e] = (__bf16)xs[e];
    return h;
}

// ============ fused preprocessing: wsplit_t + pw split + bias + td + dw + absplit ====
// blocks [0,288): wsplit_t; [288,432): pw split; [432,440): bias; [440,444): td;
// [444, 444+6144): depthwise (3072) + absplit (3072)
__global__ __launch_bounds__(256) void k_pre(
        const float* __restrict__ Wq, const float* __restrict__ Wk,
        const float* __restrict__ Wv, const float* __restrict__ coW,
        const float* __restrict__ pww, const float* __restrict__ cob,
        const float* __restrict__ sepb, const float* __restrict__ td,
        const int* __restrict__ mask, const float* __restrict__ Kin,
        const float* __restrict__ dww, const float* __restrict__ Q,
        const float* __restrict__ V,
        __bf16* __restrict__ Whi, __bf16* __restrict__ Wlo,
        float* __restrict__ biasb, float* __restrict__ td_sm,
        __bf16* __restrict__ dwbf, __bf16* __restrict__ qbf,
        __bf16* __restrict__ vbf) {
    __shared__ float shmem[64 * 65];
    int bid = blockIdx.x;
    int tid = threadIdx.x;
    if (bid < 288) {
        // ---- transposed weight split ----
        int z = bid / 72, rem = bid % 72;
        int n0 = (rem % 6) * 64, k0 = (rem / 6) * 64;
        const float* src = (z == 0) ? Wq : (z == 1) ? Wk : (z == 2) ? Wv : coW;
        float (*tile)[65] = (float(*)[65])shmem;
        int r = tid >> 2, cq = tid & 3;
#pragma unroll
        for (int e = 0; e < 4; ++e) {
            float4 v = *(const float4*)&src[(size_t)(k0 + r) * AHc + n0 + cq * 16 + e * 4];
            tile[r][cq * 16 + e * 4 + 0] = v.x;
            tile[r][cq * 16 + e * 4 + 1] = v.y;
            tile[r][cq * 16 + e * 4 + 2] = v.z;
            tile[r][cq * 16 + e * 4 + 3] = v.w;
        }
        __syncthreads();
        float x[16];
#pragma unroll
        for (int e = 0; e < 16; ++e) x[e] = tile[cq * 16 + e][r];
        bf16x8 h0, l0, h1, l1;
        split8r(x, h0, l0);
        split8r(x + 8, h1, l1);
        size_t dst = ((size_t)(z * AHc + n0 + r)) * HIDC + k0 + cq * 16;
        *(bf16x8*)(Whi + dst)     = h0;
        *(bf16x8*)(Whi + dst + 8) = h1;
        *(bf16x8*)(Wlo + dst)     = l0;
        *(bf16x8*)(Wlo + dst + 8) = l1;
        return;
    }
    if (bid < 432) {
        // ---- pw_w split (z=4, already [n][k]) ----
        int idx = (bid - 288) * 256 + tid;             // over AHc*HIDC/8
        bf16x8 hi, lo;
        split8(pww + (size_t)idx * 8, hi, lo);
        size_t dst = (size_t)4 * AHc * HIDC + (size_t)idx * 8;
        *(bf16x8*)(Whi + dst) = hi;
        *(bf16x8*)(Wlo + dst) = lo;
        return;
    }
    if (bid < 440) {
        int idx = (bid - 432) * 256 + tid;
        if (idx < 5 * AHc) {
            int z = idx / AHc, n = idx % AHc;
            biasb[idx] = (z == 3) ? cob[n] : (z == 4) ? sepb[n] : 0.f;
        }
        return;
    }
    if (bid < 444) {
        // ---- td softmax, one block per batch ----
        int b = bid - 440;
        float* red = shmem;          // 256
        float* tv  = shmem + 256;    // 1024
        float ls = 0.f;
        for (int j = tid; j < Ss; j += 256) {
            float v = td[b * Ss + j];
            tv[j] = v;
            ls += v * v;
        }
        red[tid] = ls; __syncthreads();
        for (int s = 128; s > 0; s >>= 1) { if (tid < s) red[tid] += red[tid + s]; __syncthreads(); }
        float norm = fmaxf(sqrtf(red[0]), 1e-12f);
        __syncthreads();
        float lm = -3e38f;
        for (int j = tid; j < Ss; j += 256) {
            float v = mask[b * Ss + j] ? tv[j] / norm : -1e4f;
            tv[j] = v;
            lm = fmaxf(lm, v);
        }
        red[tid] = lm; __syncthreads();
        for (int s = 128; s > 0; s >>= 1) { if (tid < s) red[tid] = fmaxf(red[tid], red[tid + s]); __syncthreads(); }
        float m = red[0]; __syncthreads();
        float lsum = 0.f;
        for (int j = tid; j < Ss; j += 256) {
            float e = expf(tv[j] - m);
            tv[j] = e;
            lsum += e;
        }
        red[tid] = lsum; __syncthreads();
        for (int s = 128; s > 0; s >>= 1) { if (tid < s) red[tid] += red[tid + s]; __syncthreads(); }
        float inv = 1.f / red[0];
        __syncthreads();
        for (int j = tid; j < Ss; j += 256)
            td_sm[b * Ss + j] = tv[j] * inv;
        return;
    }
    int db = bid - 444;
    if (db < 3072) {
        // ---- depthwise conv -> bf16 ----
        int idx = db * 256 + tid;                      // over B*S*HID/4
        int c4 = idx % (HIDC / 4);
        int s  = (idx / (HIDC / 4)) % Ss;
        int b  = idx / ((HIDC / 4) * Ss);
        int c  = c4 * 4;
        float wv[4][KSc];
#pragma unroll
        for (int j = 0; j < 4; ++j)
#pragma unroll
            for (int k = 0; k < KSc; ++k) wv[j][k] = dww[(c + j) * KSc + k];
        float4 acc = {0.f, 0.f, 0.f, 0.f};
#pragma unroll
        for (int k = 0; k < KSc; ++k) {
            int sp = s + k - PADc;
            if (sp >= 0 && sp < Ss) {
                float4 v = *(const float4*)&Kin[(size_t)(b * Ss + sp) * HIDC + c];
                acc.x += v.x * wv[0][k]; acc.y += v.y * wv[1][k];
                acc.z += v.z * wv[2][k]; acc.w += v.w * wv[3][k];
            }
        }
        bf16x4 o = {(__bf16)acc.x, (__bf16)acc.y, (__bf16)acc.z, (__bf16)acc.w};
        *(bf16x4*)(dwbf + (size_t)idx * 4) = o;
    } else {
        // ---- Q/V pre-convert ----
        const int n8 = MRr * HIDC / 8;
        int idx = (db - 3072) * 256 + tid;             // over 2 * MR*HID/8
        if (idx < n8) {
            *(bf16x8*)(qbf + (size_t)idx * 8) = cvt8(Q + (size_t)idx * 8);
        } else {
            int i = idx - n8;
            *(bf16x8*)(vbf + (size_t)i * 8) = cvt8(V + (size_t)i * 8);
        }
    }
}

// ---------------- batched MFMA GEMM (2-term: ah*(bh+bl)) ----------------
// A (bf16 pre-split, except z=1) and B both staged via global_load_lds into linear
// [128][32] LDS with granule XOR swizzle: slot s of row r holds global granule
// s ^ (r & 3). Read granule q of row r at slot q ^ (r&3).
// Fused epilogues: z=0 -> mq f32 + qh bf16; z=1 -> kh/kl bf16; z=2 -> vt bf16
// transposed (no f32 C at all); z=3/4 -> co/mkc f32 + bias.
__global__ __launch_bounds__(256) void k_gemm5(
        const __bf16* __restrict__ qbf, const float* __restrict__ Kin,
        const __bf16* __restrict__ vbf, const __bf16* __restrict__ dwbf,
        const __bf16* __restrict__ Whi, const __bf16* __restrict__ Wlo,
        const float* __restrict__ biasb, float* __restrict__ Call,
        __bf16* __restrict__ kh, __bf16* __restrict__ kl,
        __bf16* __restrict__ qh, __bf16* __restrict__ vt) {
    __shared__ __attribute__((aligned(16))) __bf16 As [128 * 32];
    __shared__ __attribute__((aligned(16))) __bf16 BsH[128 * 32];
    __shared__ __attribute__((aligned(16))) __bf16 BsL[128 * 32];

    int wg = blockIdx.x + 3 * (blockIdx.y + 32 * blockIdx.z);   // 0..479
    int n2 = (wg & 7) * 60 + (wg >> 3);                         // bijective (480%8==0)
    int bxx = n2 % 3, byy = (n2 / 3) % 32, z = n2 / 96;

    int m0 = byy * 128, n0 = bxx * 128;
    int tid = threadIdx.x;
    int wave = tid >> 6, lane = tid & 63, quad = lane >> 4, l15 = lane & 15;

    int lrow = lane >> 2;                                // 0..15 within instr
    int lswz = 8 * ((lane & 3) ^ (lrow & 3));            // swizzled src granule offset

    // B staging (gl_lds): instr p = wave*2+q covers rows p*16..p*16+15
    int brow = wave * 32 + lrow;
    const __bf16* BhG0 = Whi + ((size_t)(z * AHc + n0 + brow)) * HIDC + lswz;
    const __bf16* BhG1 = BhG0 + (size_t)16 * HIDC;
    const __bf16* BlG0 = Wlo + ((size_t)(z * AHc + n0 + brow)) * HIDC + lswz;
    const __bf16* BlG1 = BlG0 + (size_t)16 * HIDC;
    __bf16* BhL0 = BsH + (wave * 2 + 0) * 512;
    __bf16* BhL1 = BsH + (wave * 2 + 1) * 512;
    __bf16* BlL0 = BsL + (wave * 2 + 0) * 512;
    __bf16* BlL1 = BsL + (wave * 2 + 1) * 512;

    // A staging (gl_lds path, z != 1)
    const __bf16* Abf = (z == 0) ? qbf : (z == 4) ? dwbf : vbf;
    const __bf16* AG0 = Abf + ((size_t)(m0 + wave * 32 + lrow)) * HIDC + lswz;
    const __bf16* AG1 = AG0 + (size_t)16 * HIDC;
    __bf16* AL0 = As + (wave * 2 + 0) * 512;
    __bf16* AL1 = As + (wave * 2 + 1) * 512;

    // A staging (f32 path, z == 1): swizzled ds_write of cvt'd granule pairs
    int sr = tid >> 1;
    int sk = (tid & 1) * 16;
    const float* Arow = Kin + (size_t)(m0 + sr) * HIDC + sk;
    int g0 = sk >> 3;                                    // 0 or 2
    int d0 = sr * 32 + ((g0       ^ (sr & 3)) * 8);
    int d1 = sr * 32 + (((g0 + 1) ^ (sr & 3)) * 8);

    int swz = (quad ^ (l15 & 3)) * 8;                    // swizzled read offset
    f32x4 acc[4][4] = {};

    for (int k0 = 0; k0 < HIDC; k0 += 32) {
        if (z == 1) {
            const float* ap = Arow + k0;
            *(bf16x8*)&As[d0] = cvt8(ap);
            *(bf16x8*)&As[d1] = cvt8(ap + 8);
        } else {
            gl_lds16(AG0 + k0, AL0);
            gl_lds16(AG1 + k0, AL1);
        }
        gl_lds16(BhG0 + k0, BhL0);
        gl_lds16(BhG1 + k0, BhL1);
        gl_lds16(BlG0 + k0, BlL0);
        gl_lds16(BlG1 + k0, BlL1);
        __syncthreads();

        int mrow = (wave >> 1) * 64 + l15;
        int nrow = (wave & 1) * 64 + l15;
        bf16x8 ah[4], bh[4], bl[4];
#pragma unroll
        for (int mt = 0; mt < 4; ++mt)
            ah[mt] = *(bf16x8*)&As[(mrow + mt * 16) * 32 + swz];
#pragma unroll
        for (int nt = 0; nt < 4; ++nt) {
            bh[nt] = *(bf16x8*)&BsH[(nrow + nt * 16) * 32 + swz];
            bl[nt] = *(bf16x8*)&BsL[(nrow + nt * 16) * 32 + swz];
        }
#pragma unroll
        for (int mt = 0; mt < 4; ++mt)
#pragma unroll
            for (int nt = 0; nt < 4; ++nt) {
                acc[mt][nt] = __builtin_amdgcn_mfma_f32_16x16x32_bf16(ah[mt], bh[nt], acc[mt][nt], 0, 0, 0);
                acc[mt][nt] = __builtin_amdgcn_mfma_f32_16x16x32_bf16(ah[mt], bl[nt], acc[mt][nt], 0, 0, 0);
            }
        __syncthreads();
    }

    if (z == 1) {
        // zero bias; emit kh/kl bf16 directly (K used only by attention)
#pragma unroll
        for (int nt = 0; nt < 4; ++nt) {
            int n = n0 + (wave & 1) * 64 + nt * 16 + l15;
#pragma unroll
            for (int mt = 0; mt < 4; ++mt) {
#pragma unroll
                for (int r = 0; r < 4; ++r) {
                    int m = m0 + (wave >> 1) * 64 + mt * 16 + quad * 4 + r;
                    float v = acc[mt][nt][r];
                    __bf16 hv = (__bf16)v;
                    kh[(size_t)m * AHc + n] = hv;
                    kl[(size_t)m * AHc + n] = (__bf16)(v - (float)hv);
                }
            }
        }
    } else if (z == 2) {
        // zero bias; emit vt bf16 transposed directly: vt[(b*H+h)*D+d][s]
        int b = m0 >> 10;
#pragma unroll
        for (int nt = 0; nt < 4; ++nt) {
            int n = (wave & 1) * 64 + nt * 16 + l15;     // 0..127 within n0 tile
            int gn = n0 + n;                             // global col = h*64+d
            int h = gn >> 6, d = gn & 63;
#pragma unroll
            for (int mt = 0; mt < 4; ++mt) {
                int m = m0 + (wave >> 1) * 64 + mt * 16 + quad * 4;
                int s = m & (Ss - 1);
                bf16x4 o = {(__bf16)acc[mt][nt][0], (__bf16)acc[mt][nt][1],
                            (__bf16)acc[mt][nt][2], (__bf16)acc[mt][nt][3]};
                *(bf16x4*)&vt[((size_t)((b * Hh + h) * Dd + d)) * Ss + s] = o;
            }
        }
    } else if (z == 0) {
        // zero bias; write mq f32 (k_ckconv) + qh bf16 (attention)
#pragma unroll
        for (int nt = 0; nt < 4; ++nt) {
            int n = n0 + (wave & 1) * 64 + nt * 16 + l15;
#pragma unroll
            for (int mt = 0; mt < 4; ++mt) {
#pragma unroll
                for (int r = 0; r < 4; ++r) {
                    int m = m0 + (wave >> 1) * 64 + mt * 16 + quad * 4 + r;
                    float v = acc[mt][nt][r];
                    Call[(size_t)m * AHc + n] = v;
                    qh[(size_t)m * AHc + n] = (__bf16)v;
                }
            }
        }
    } else {
        float* Cz = Call + (size_t)z * MRr * AHc;
        const float* bz = biasb + z * AHc;
#pragma unroll
        for (int nt = 0; nt < 4; ++nt) {
            int n = n0 + (wave & 1) * 64 + nt * 16 + l15;
            float bias = bz[n];
#pragma unroll
            for (int mt = 0; mt < 4; ++mt) {
#pragma unroll
                for (int r = 0; r < 4; ++r) {
                    int m = m0 + (wave >> 1) * 64 + mt * 16 + quad * 4 + r;
                    Cz[(size_t)m * AHc + n] = acc[mt][nt][r] + bias;
                }
            }
        }
    }
}

// ============ fused ck linear + softmax + dynamic conv output ============
// Block = 4 rows (4 waves of 64). ckv stays in LDS; cksm buffer eliminated.
__global__ __launch_bounds__(256) void k_ckconv(const float* __restrict__ mkc,
                                                const float* __restrict__ mq,
                                                const float* __restrict__ ckW,
                                                const float* __restrict__ ckb,
                                                const float* __restrict__ co,
                                                float* __restrict__ out) {
    int tid = threadIdx.x;
    int lr = tid >> 6, lane = tid & 63;
    int row = blockIdx.x * 4 + lr;          // b*S + s
    __shared__ float ca[4][AHc];
    __shared__ float ckv[4][Hh * KSc];
    for (int o = lane; o < AHc; o += 64)
        ca[lr][o] = mkc[(size_t)row * AHc + o] * mq[(size_t)row * AHc + o];
    __syncthreads();
    if (lane < Hh * KSc) {
        float acc = ckb[lane];
        for (int o = 0; o < AHc; ++o)
            acc += ca[lr][o] * ckW[o * (Hh * KSc) + lane];
        ckv[lr][lane] = acc;
    }
    __syncthreads();
    if (lane < Hh) {
        float m = -3e38f;
#pragma unroll
        for (int k = 0; k < KSc; ++k) m = fmaxf(m, ckv[lr][lane * KSc + k]);
        float e[KSc];
        float s = 0.f;
#pragma unroll
        for (int k = 0; k < KSc; ++k) { e[k] = expf(ckv[lr][lane * KSc + k] - m); s += e[k]; }
        float inv = 1.f / s;
#pragma unroll
        for (int k = 0; k < KSc; ++k) ckv[lr][lane * KSc + k] = e[k] * inv;
    }
    __syncthreads();
    // conv output for the block's 4 rows: 4 * 96 float4 items
#pragma unroll
    for (int e = 0; e < 2; ++e) {
        int it = e * 256 + tid;
        if (it >= 4 * (AHc / 4)) break;
        int r4i = it / (AHc / 4), dq = it % (AHc / 4);
        int h = dq >> 4, d4 = dq & 15;
        int row2 = blockIdx.x * 4 + r4i;
        int s = row2 & (Ss - 1), b = row2 >> 10;
        float4 acc = {0.f, 0.f, 0.f, 0.f};
#pragma unroll
        for (int k = 0; k < KSc; ++k) {
            int sp = s + k - PADc;
            if (sp >= 0 && sp < Ss) {
                float4 v = *(const float4*)&co[(size_t)(b * Ss + sp) * AHc + h * Dd + d4 * 4];
                float wv = ckv[r4i][h * KSc + k];
                acc.x += wv * v.x; acc.y += wv * v.y; acc.z += wv * v.z; acc.w += wv * v.w;
            }
        }
        *(float4*)&out[(size_t)row2 * (2 * AHc) + AHc + h * Dd + d4 * 4] = acc;
    }
}

// ---------------- attention: 16 q-rows/block, 512 threads, XCD-chunked remap ------
__device__ __forceinline__ int scix(int m, int j) {
    return m * 1024 + (j ^ (((m ^ (j >> 6)) & 7) << 2));
}

__global__ __launch_bounds__(512, 4) void k_attn(const __bf16* __restrict__ qh,
                                              const __bf16* __restrict__ kh, const __bf16* __restrict__ kl,
                                              const __bf16* __restrict__ vt,
                                              const int* __restrict__ mask,
                                              const float* __restrict__ td_sm, const float* __restrict__ gammas,
                                              float* __restrict__ out) {
    __shared__ float sc[16 * 1024];      // 64 KB exactly
    int wg = blockIdx.x + 64 * blockIdx.y;
    int n  = (wg & 7) * 192 + (wg >> 3);
    int bx = n & 63, by = n >> 6;
    int i0 = bx * 16;
    int h = by % Hh, b = by / Hh;
    int tid = threadIdx.x;
    int w = tid >> 6, lane = tid & 63, quad = lane >> 4, l15 = lane & 15;
    int jw = w * 128;                     // this wave's j-range [jw, jw+128)

    // ---- phase 1: QK^T via MFMA: q_hi*(k_hi + k_lo) ----
    bf16x8 a_hi[2];
    {
        size_t qoff = (size_t)(b * Ss + i0 + l15) * AHc + h * Dd + quad * 8;
        a_hi[0] = *(const bf16x8*)(qh + qoff);
        a_hi[1] = *(const bf16x8*)(qh + qoff + 32);
    }
#pragma unroll 4
    for (int t = 0; t < 8; ++t) {
        int jt = jw + t * 16;
        size_t koff = (size_t)(b * Ss + jt + l15) * AHc + h * Dd + quad * 8;
        f32x4 acc = {0.f, 0.f, 0.f, 0.f};
#pragma unroll
        for (int kc = 0; kc < 2; ++kc) {
            bf16x8 khv = *(const bf16x8*)(kh + koff + kc * 32);
            bf16x8 klv = *(const bf16x8*)(kl + koff + kc * 32);
            acc = __builtin_amdgcn_mfma_f32_16x16x32_bf16(a_hi[kc], khv, acc, 0, 0, 0);
            acc = __builtin_amdgcn_mfma_f32_16x16x32_bf16(a_hi[kc], klv, acc, 0, 0, 0);
        }
#pragma unroll
        for (int r = 0; r < 4; ++r)
            sc[scix(quad * 4 + r, jt + l15)] = acc[r] * 0.125f;   // C: col=l15, row=quad*4+r
    }
    __syncthreads();

    // ---- phase 2: softmax -> cumsum -> decay -> softmax2 ----
    // wave owns rows w*2 (A) and w*2+1 (B); the two rows' chains are explicitly
    // interleaved step-by-step for 2x issue density on the serial reductions.
    const int* mrow = mask + b * Ss;
    const float* tdrow = td_sm + b * Ss;
    float gamma = -log1pf(expf(gammas[h]));   // -softplus
    int jb = lane << 4;
    __attribute__((aligned(16))) int marr[16];
    {
        const int4* mp = (const int4*)(mrow + jb);
#pragma unroll
        for (int k = 0; k < 4; ++k) ((int4*)marr)[k] = mp[k];
    }
    __attribute__((aligned(16))) float tdv[16];
    {
        const float4* tp = (const float4*)(tdrow + jb);
#pragma unroll
        for (int k = 0; k < 4; ++k) ((float4*)tdv)[k] = tp[k];
    }

    {
        int mA = w * 2, mB = mA + 1;
        int iA = i0 + mA, iB = i0 + mB;
        __attribute__((aligned(16))) float sA[16], sB[16];
        float pA[16], pB[16];
#pragma unroll
        for (int g = 0; g < 4; ++g) {
            *(f32x4*)(sA + 4 * g) = *(const f32x4*)&sc[scix(mA, jb + 4 * g)];
            *(f32x4*)(sB + 4 * g) = *(const f32x4*)&sc[scix(mB, jb + 4 * g)];
        }
        float mxA = -1e30f, mxB = -1e30f;
#pragma unroll
        for (int jj = 0; jj < 16; ++jj) {
            mxA = fmaxf(mxA, marr[jj] ? sA[jj] : -1e30f);
            mxB = fmaxf(mxB, marr[jj] ? sB[jj] : -1e30f);
        }
#pragma unroll
        for (int d = 1; d < 64; d <<= 1) {
            mxA = fmaxf(mxA, __shfl_xor(mxA, d));
            mxB = fmaxf(mxB, __shfl_xor(mxB, d));
        }
#pragma unroll
        for (int jj = 0; jj < 16; ++jj) {
            pA[jj] = marr[jj] ? __expf(sA[jj] - mxA) : 0.f;
            pB[jj] = marr[jj] ? __expf(sB[jj] - mxB) : 0.f;
        }
#pragma unroll
        for (int jj = 1; jj < 16; ++jj) { pA[jj] += pA[jj - 1]; pB[jj] += pB[jj - 1]; }
        float tA = pA[15], tB = pB[15];
        float incA = tA, incB = tB;
#pragma unroll
        for (int dlt = 1; dlt < 64; dlt <<= 1) {
            float vA = __shfl_up(incA, dlt);
            float vB = __shfl_up(incB, dlt);
            if (lane >= dlt) { incA += vA; incB += vB; }
        }
        float offA = incA - tA, offB = incB - tB;
        float totA = __shfl(incA, 63), totB = __shfl(incB, 63);
        float invA = 1.f / fmaxf(totA, 1e-30f), invB = 1.f / fmaxf(totB, 1e-30f);
        float mx2A = -1e30f, mx2B = -1e30f;
#pragma unroll
        for (int jj = 0; jj < 16; ++jj) {
            int j = jb + jj;
            float cumA = pA[jj] + offA, cumB = pB[jj] + offB;
            float posA = fabsf((float)(j - iA));
            float posB = fabsf((float)(j - iB));
            float dsA = sqrtf(fmaxf((totA - cumA) * invA * posA, 0.f));
            float dsB = sqrtf(fmaxf((totB - cumB) * invB * posB, 0.f));
            float teA = fminf(fmaxf(__expf(dsA * gamma), 1e-5f), 1e5f);
            float teB = fminf(fmaxf(__expf(dsB * gamma), 1e-5f), 1e5f);
            float tdj = tdv[jj];
            float multA = teA - ((j < iA) ? tdj : 0.f);
            float multB = teB - ((j < iB) ? tdj : 0.f);
            float s2A = marr[jj] ? sA[jj] * multA : -1e8f;
            float s2B = marr[jj] ? sB[jj] * multB : -1e8f;
            sA[jj] = s2A; sB[jj] = s2B;
            mx2A = fmaxf(mx2A, s2A); mx2B = fmaxf(mx2B, s2B);
        }
#pragma unroll
        for (int d = 1; d < 64; d <<= 1) {
            mx2A = fmaxf(mx2A, __shfl_xor(mx2A, d));
            mx2B = fmaxf(mx2B, __shfl_xor(mx2B, d));
        }
        float smA = 0.f, smB = 0.f;
#pragma unroll
        for (int jj = 0; jj < 16; ++jj) {
            sA[jj] = __expf(sA[jj] - mx2A); smA += sA[jj];
            sB[jj] = __expf(sB[jj] - mx2B); smB += sB[jj];
        }
#pragma unroll
        for (int d = 1; d < 64; d <<= 1) {
            smA += __shfl_xor(smA, d);
            smB += __shfl_xor(smB, d);
        }
        float i2A = 1.f / smA, i2B = 1.f / smB;
#pragma unroll
        for (int jj = 0; jj < 16; ++jj) { sA[jj] *= i2A; sB[jj] *= i2B; }
#pragma unroll
        for (int g = 0; g < 4; ++g) {
            *(f32x4*)&sc[scix(mA, jb + 4 * g)] = *(const f32x4*)(sA + 4 * g);
            *(f32x4*)&sc[scix(mB, jb + 4 * g)] = *(const f32x4*)(sB + 4 * g);
        }
    }
    __syncthreads();

    // ---- phase 3: PV via MFMA: (p_hi + p_lo) * v_hi; V pre-transposed bf16 [d][j] ----
    f32x4 oacc[4] = {};
    const __bf16* vtb = vt + (size_t)(b * Hh + h) * Dd * Ss;
#pragma unroll
    for (int kc = 0; kc < 4; ++kc) {
        int j0 = jw + kc * 32 + quad * 8;        // this lane's 8 j indices (k = quad*8+e)
        __attribute__((aligned(16))) float x[8];
        *(f32x4*)x       = *(const f32x4*)&sc[scix(l15, j0)];
        *(f32x4*)(x + 4) = *(const f32x4*)&sc[scix(l15, j0 + 4)];
        bf16x8 p_hi, p_lo;
        split8r(x, p_hi, p_lo);
#pragma unroll
        for (int nt = 0; nt < 4; ++nt) {
            int d = nt * 16 + l15;
            bf16x8 vv = *(const bf16x8*)(vtb + (size_t)d * Ss + j0);
            oacc[nt] = __builtin_amdgcn_mfma_f32_16x16x32_bf16(p_hi, vv, oacc[nt], 0, 0, 0);
            oacc[nt] = __builtin_amdgcn_mfma_f32_16x16x32_bf16(p_lo, vv, oacc[nt], 0, 0, 0);
        }
    }
    __syncthreads();                      // all waves done reading sc before reuse
#pragma unroll
    for (int nt = 0; nt < 4; ++nt)
#pragma unroll
        for (int r = 0; r < 4; ++r)
            sc[w * 1024 + (quad * 4 + r) * 64 + nt * 16 + l15] = oacc[nt][r];
    __syncthreads();
#pragma unroll
    for (int e = 0; e < 2; ++e) {
        int idx = e * 512 + tid;
        int m = idx >> 6, dd = idx & 63;
        float v = 0.f;
#pragma unroll
        for (int ww = 0; ww < 8; ++ww) v += sc[ww * 1024 + idx];
        out[(size_t)(b * Ss + i0 + m) * (2 * AHc) + h * Dd + dd] = v;
    }
}

extern "C" void kernel_launch(void* const* d_in, const int* in_sizes, int n_in,
                              void* d_out, int out_size, void* d_ws, size_t ws_size,
                              hipStream_t stream) {
    const float* Q    = (const float*)d_in[0];
    const float* Kin  = (const float*)d_in[1];
    const float* V    = (const float*)d_in[2];
    const float* td   = (const float*)d_in[3];
    const int*   mask = (const int*)d_in[4];
    const float* Wq   = (const float*)d_in[5];
    const float* Wk   = (const float*)d_in[6];
    const float* Wv   = (const float*)d_in[7];
    const float* dww  = (const float*)d_in[8];
    const float* pww  = (const float*)d_in[9];
    const float* sepb = (const float*)d_in[10];
    const float* ckW  = (const float*)d_in[11];
    const float* ckb  = (const float*)d_in[12];
    const float* coW  = (const float*)d_in[13];
    const float* cob  = (const float*)d_in[14];
    const float* gam  = (const float*)d_in[15];
    float* out = (float*)d_out;
    float* ws = (float*)d_ws;

    float* mq    = ws;                              // z=0 C (f32)
    float* mks   = mq    + (size_t)MRr * AHc;       // z=1 slot -> kh/kl bf16
    float* mvs   = mks   + (size_t)MRr * AHc;       // z=2 slot -> vt + qh bf16
    float* co    = mvs   + (size_t)MRr * AHc;       // z=3
    float* mkc   = co    + (size_t)MRr * AHc;       // z=4
    float* dwr   = mkc   + (size_t)MRr * AHc;       // MR*HID f32 region
    float* tdsm  = dwr   + (size_t)MRr * HIDC;      // B*S
    float* biasb = tdsm  + (size_t)Bb * Ss;         // 5*384

    // dwr region: pre-gemm staging [dwbf | qbf] bf16 (dead after k_gemm5)
    __bf16* dwbf = (__bf16*)dwr;
    __bf16* qbf  = (__bf16*)(dwr + (size_t)MRr * HIDC / 2);
    // attention operands live in dedicated ws slots (no aliasing with gemm inputs):
    __bf16* kh = (__bf16*)mks;                      // z=1 epilogue output
    __bf16* kl = kh + (size_t)MRr * AHc;
    __bf16* vt = (__bf16*)mvs;                      // z=2 epilogue output (transposed V)
    __bf16* qh = vt + (size_t)MRr * AHc;            // z=0 epilogue output

    // d_out scratch: Whi/Wlo (5.9 MB) + vbf (6.3 MB) — dead after k_gemm5
    __bf16* Whi = (__bf16*)d_out;
    __bf16* Wlo = Whi + (size_t)5 * AHc * HIDC;
    __bf16* vbf = Wlo + (size_t)5 * AHc * HIDC;

    k_pre<<<6588, 256, 0, stream>>>(Wq, Wk, Wv, coW, pww, cob, sepb, td, mask,
                                    Kin, dww, Q, V, Whi, Wlo, biasb, tdsm,
                                    dwbf, qbf, vbf);

    dim3 gg(AHc / 128, MRr / 128, 5);   // 3 x 32 x 5
    k_gemm5<<<gg, 256, 0, stream>>>(qbf, Kin, vbf, dwbf, Whi, Wlo, biasb, mq, kh, kl, qh, vt);

    k_ckconv<<<MRr / 4, 256, 0, stream>>>(mkc, mq, ckW, ckb, co, out);

    dim3 ga(Ss / 16, Bb * Hh);          // 64 x 24
    k_attn<<<ga, 512, 0, stream>>>(qh, kh, kl, vt, mask, tdsm, gam, out);
}